// Round 1
// baseline (3369.295 us; speedup 1.0000x reference)
//
#include <hip/hip_runtime.h>
#include <cstdint>

#define NN 50000
#define NE 800000

// ---------------- tiny precompute: M[h][k] = sum_c lin_edge[(h*32+c)*4+k]*att_edge[h*32+c]
__global__ void k_prep(const float* __restrict__ le1, const float* __restrict__ ae1,
                       const float* __restrict__ le2, const float* __restrict__ ae2,
                       float* __restrict__ M)
{
    int t = threadIdx.x;
    if (t >= 32) return;
    const float* le = (t < 16) ? le1 : le2;
    const float* ae = (t < 16) ? ae1 : ae2;
    int hk = t & 15, h = hk >> 2, k = hk & 3;
    float s = 0.f;
    for (int c = 0; c < 32; ++c)
        s += le[(h * 32 + c) * 4 + k] * ae[h * 32 + c];
    M[t] = s;
}

// ---------------- edge encoder: e4 = W2*relu(W1*ea+b1)+b2  (per edge)
__global__ __launch_bounds__(256) void k_edge(const float* __restrict__ ea,
                                              const float* __restrict__ w1,
                                              const float* __restrict__ b1,
                                              const float* __restrict__ w2,
                                              const float* __restrict__ b2,
                                              float* __restrict__ e4out)
{
    __shared__ float sw1[256], sb1[32], sw2[128], sb2[4];
    int t = threadIdx.x;
    sw1[t] = w1[t];
    if (t < 128) sw2[t] = w2[t];
    if (t < 32)  sb1[t] = b1[t];
    if (t < 4)   sb2[t] = b2[t];
    __syncthreads();
    int e = blockIdx.x * 256 + t;
    if (e >= NE) return;
    float4 x0 = *(const float4*)(ea + (size_t)e * 8);
    float4 x1 = *(const float4*)(ea + (size_t)e * 8 + 4);
    float o0 = sb2[0], o1 = sb2[1], o2 = sb2[2], o3 = sb2[3];
    #pragma unroll
    for (int j = 0; j < 32; ++j) {
        const float* w = sw1 + j * 8;
        float s = sb1[j] + w[0]*x0.x + w[1]*x0.y + w[2]*x0.z + w[3]*x0.w
                         + w[4]*x1.x + w[5]*x1.y + w[6]*x1.z + w[7]*x1.w;
        s = fmaxf(s, 0.f);
        o0 += sw2[0*32+j] * s; o1 += sw2[1*32+j] * s;
        o2 += sw2[2*32+j] * s; o3 += sw2[3*32+j] * s;
    }
    *(float4*)(e4out + (size_t)e * 4) = make_float4(o0, o1, o2, o3);
}

// ---------------- generic fp32 GEMM: C[M,128] = A[M,K] * W[128,K]^T (+bias)
// 128x128 tile, 256 threads, 8x8 microtile, BK=16
__global__ __launch_bounds__(256) void gemm_nt(const float* __restrict__ A, int lda, int K,
                                               const float* __restrict__ W,
                                               const float* __restrict__ bias,
                                               float* __restrict__ C, int ldc, int M)
{
    __shared__ float As[16][128];
    __shared__ float Ws[16][128];
    int t = threadIdx.x;
    int m0 = blockIdx.x * 128;
    int ty = t >> 4, tx = t & 15;
    float acc[8][8];
    #pragma unroll
    for (int i = 0; i < 8; ++i)
        #pragma unroll
        for (int j = 0; j < 8; ++j) acc[i][j] = 0.f;
    int lr = t >> 1;
    int lk = (t & 1) * 8;
    for (int k0 = 0; k0 < K; k0 += 16) {
        int ar = m0 + lr; if (ar >= M) ar = M - 1;
        const float* ap = A + (size_t)ar * lda + k0 + lk;
        float4 a0 = *(const float4*)ap, a1 = *(const float4*)(ap + 4);
        const float* wp = W + (size_t)lr * K + k0 + lk;
        float4 w0 = *(const float4*)wp, w1 = *(const float4*)(wp + 4);
        As[lk+0][lr]=a0.x; As[lk+1][lr]=a0.y; As[lk+2][lr]=a0.z; As[lk+3][lr]=a0.w;
        As[lk+4][lr]=a1.x; As[lk+5][lr]=a1.y; As[lk+6][lr]=a1.z; As[lk+7][lr]=a1.w;
        Ws[lk+0][lr]=w0.x; Ws[lk+1][lr]=w0.y; Ws[lk+2][lr]=w0.z; Ws[lk+3][lr]=w0.w;
        Ws[lk+4][lr]=w1.x; Ws[lk+5][lr]=w1.y; Ws[lk+6][lr]=w1.z; Ws[lk+7][lr]=w1.w;
        __syncthreads();
        #pragma unroll
        for (int k = 0; k < 16; ++k) {
            float a[8], b[8];
            *(float4*)(a)     = *(const float4*)&As[k][ty * 8];
            *(float4*)(a + 4) = *(const float4*)&As[k][ty * 8 + 4];
            *(float4*)(b)     = *(const float4*)&Ws[k][tx * 8];
            *(float4*)(b + 4) = *(const float4*)&Ws[k][tx * 8 + 4];
            #pragma unroll
            for (int i = 0; i < 8; ++i)
                #pragma unroll
                for (int j = 0; j < 8; ++j)
                    acc[i][j] = fmaf(a[i], b[j], acc[i][j]);
        }
        __syncthreads();
    }
    float bv[8];
    #pragma unroll
    for (int j = 0; j < 8; ++j) bv[j] = bias ? bias[tx * 8 + j] : 0.f;
    #pragma unroll
    for (int i = 0; i < 8; ++i) {
        int r = m0 + ty * 8 + i;
        if (r < M) {
            float* cp = C + (size_t)r * ldc + tx * 8;
            *(float4*)cp       = make_float4(acc[i][0]+bv[0], acc[i][1]+bv[1], acc[i][2]+bv[2], acc[i][3]+bv[3]);
            *(float4*)(cp + 4) = make_float4(acc[i][4]+bv[4], acc[i][5]+bv[5], acc[i][6]+bv[6], acc[i][7]+bv[7]);
        }
    }
}

// ---------------- per-node attention coefficients: as[n,h], ad[n,h]
__global__ __launch_bounds__(256) void k_att_reduce(const float* __restrict__ xs,
                                                    const float* __restrict__ att_src,
                                                    const float* __restrict__ att_dst,
                                                    float* __restrict__ as_out,
                                                    float* __restrict__ ad_out)
{
    __shared__ float ssrc[128], sdst[128];
    int t = threadIdx.x;
    if (t < 128) { ssrc[t] = att_src[t]; sdst[t] = att_dst[t]; }
    __syncthreads();
    int n = blockIdx.x * 256 + t;
    if (n >= NN) return;
    float s[4] = {0,0,0,0}, d[4] = {0,0,0,0};
    const float4* xr = (const float4*)(xs + (size_t)n * 128);
    #pragma unroll
    for (int q = 0; q < 32; ++q) {
        float4 v = xr[q];
        int h = q >> 3;
        const float* aw = ssrc + q * 4;
        const float* dw = sdst + q * 4;
        s[h] += v.x*aw[0] + v.y*aw[1] + v.z*aw[2] + v.w*aw[3];
        d[h] += v.x*dw[0] + v.y*dw[1] + v.z*dw[2] + v.w*dw[3];
    }
    *(float4*)(as_out + (size_t)n * 4) = make_float4(s[0], s[1], s[2], s[3]);
    *(float4*)(ad_out + (size_t)n * 4) = make_float4(d[0], d[1], d[2], d[3]);
}

// ---------------- per-edge: ex = exp(leaky(as[src]+ad[dst]+M*e4)), denom[dst] += ex
__global__ __launch_bounds__(256) void k_edge_soft(const int* __restrict__ ei,
                                                   const float* __restrict__ as_in,
                                                   const float* __restrict__ ad_in,
                                                   const float* __restrict__ e4,
                                                   const float* __restrict__ Mm,
                                                   float* __restrict__ ex_out,
                                                   float* __restrict__ denom)
{
    __shared__ float sM[16];
    int t = threadIdx.x;
    if (t < 16) sM[t] = Mm[t];
    __syncthreads();
    int e = blockIdx.x * 256 + t;
    if (e >= NE) return;
    int src = ei[e], dst = ei[NE + e];
    float4 s4 = *(const float4*)(as_in + (size_t)src * 4);
    float4 d4 = *(const float4*)(ad_in + (size_t)dst * 4);
    float4 ev = *(const float4*)(e4 + (size_t)e * 4);
    float sa[4] = {s4.x, s4.y, s4.z, s4.w};
    float da[4] = {d4.x, d4.y, d4.z, d4.w};
    float ex[4];
    #pragma unroll
    for (int h = 0; h < 4; ++h) {
        float ae = sM[h*4+0]*ev.x + sM[h*4+1]*ev.y + sM[h*4+2]*ev.z + sM[h*4+3]*ev.w;
        float a = sa[h] + da[h] + ae;
        a = a > 0.f ? a : 0.2f * a;
        ex[h] = expf(a);
    }
    *(float4*)(ex_out + (size_t)e * 4) = make_float4(ex[0], ex[1], ex[2], ex[3]);
    #pragma unroll
    for (int h = 0; h < 4; ++h)
        atomicAdd(&denom[(size_t)dst * 4 + h], ex[h]);
}

// ---------------- aggregation: agg[dst, ch] += ex[e,h] * xs[src, ch]  (thread = (edge, 4-ch group))
__global__ __launch_bounds__(256) void k_agg(const int* __restrict__ ei,
                                             const float* __restrict__ ex,
                                             const float* __restrict__ xs,
                                             float* __restrict__ agg)
{
    long long gid = (long long)blockIdx.x * 256 + threadIdx.x;
    if (gid >= (long long)NE * 32) return;
    int e = (int)(gid >> 5);
    int q = (int)(gid & 31);
    int h = q >> 3;
    int src = ei[e], dst = ei[NE + e];
    float w = ex[(size_t)e * 4 + h];
    float4 v = *(const float4*)(xs + (size_t)src * 128 + q * 4);
    float* out = agg + (size_t)dst * 128 + q * 4;
    atomicAdd(out + 0, v.x * w);
    atomicAdd(out + 1, v.y * w);
    atomicAdd(out + 2, v.z * w);
    atomicAdd(out + 3, v.w * w);
}

// ---------------- conv epilogue: h = LN(elu(agg/denom + bias) + resid) -> out (row stride 384)
__global__ __launch_bounds__(256) void k_epilogue(const float* __restrict__ agg,
                                                  const float* __restrict__ denom,
                                                  const float* __restrict__ bias,
                                                  const float* __restrict__ resid,
                                                  const float* __restrict__ g,
                                                  const float* __restrict__ bln,
                                                  float* __restrict__ outp)
{
    __shared__ float red[4][2];
    int t = threadIdx.x;
    int n = blockIdx.x * 2 + (t >> 7);
    int c = t & 127;
    float r = 0.f;
    if (n < NN) {
        float v = agg[(size_t)n * 128 + c] / (denom[(size_t)n * 4 + (c >> 5)] + 1e-16f) + bias[c];
        v = v > 0.f ? v : (expf(v) - 1.f);
        r = v + resid[(size_t)n * 384 + c];
    }
    float s = r, sq = r * r;
    #pragma unroll
    for (int o = 32; o > 0; o >>= 1) {
        s  += __shfl_down(s, o, 64);
        sq += __shfl_down(sq, o, 64);
    }
    int wave = t >> 6;
    if ((t & 63) == 0) { red[wave][0] = s; red[wave][1] = sq; }
    __syncthreads();
    int base = (t >> 7) * 2;
    float S  = red[base][0] + red[base + 1][0];
    float SQ = red[base][1] + red[base + 1][1];
    float mu = S * (1.f / 128.f);
    float var = SQ * (1.f / 128.f) - mu * mu;
    float rs = rsqrtf(var + 1e-5f);
    if (n < NN)
        outp[(size_t)n * 384 + c] = (r - mu) * rs * g[c] + bln[c];
}

// ---------------- classifier + log_softmax
__global__ __launch_bounds__(256) void k_final(const float* __restrict__ hjk,
                                               const float* __restrict__ cw,
                                               const float* __restrict__ cb,
                                               float* __restrict__ out)
{
    __shared__ float scw[640], scb[5];
    int t = threadIdx.x;
    for (int i = t; i < 640; i += 256) scw[i] = cw[i];
    if (t < 5) scb[t] = cb[t];
    __syncthreads();
    int n = blockIdx.x * 256 + t;
    if (n >= NN) return;
    float acc[5] = {scb[0], scb[1], scb[2], scb[3], scb[4]};
    const float4* hr = (const float4*)(hjk + (size_t)n * 128);
    #pragma unroll
    for (int q = 0; q < 32; ++q) {
        float4 v = hr[q];
        #pragma unroll
        for (int o = 0; o < 5; ++o) {
            const float* w = scw + o * 128 + q * 4;
            acc[o] += v.x*w[0] + v.y*w[1] + v.z*w[2] + v.w*w[3];
        }
    }
    float m = acc[0];
    #pragma unroll
    for (int o = 1; o < 5; ++o) m = fmaxf(m, acc[o]);
    float sum = 0.f;
    #pragma unroll
    for (int o = 0; o < 5; ++o) sum += expf(acc[o] - m);
    float lse = logf(sum) + m;
    float* op = out + (size_t)n * 5;
    #pragma unroll
    for (int o = 0; o < 5; ++o) op[o] = acc[o] - lse;
}

__global__ void k_fill(float* __restrict__ p, float v, long long cnt)
{
    long long i = (long long)blockIdx.x * 256 + threadIdx.x;
    if (i < cnt) p[i] = v;
}

extern "C" void kernel_launch(void* const* d_in, const int* in_sizes, int n_in,
                              void* d_out, int out_size, void* d_ws, size_t ws_size,
                              hipStream_t stream)
{
    (void)in_sizes; (void)n_in; (void)out_size; (void)ws_size;
    const float* x        = (const float*)d_in[0];
    const int*   ei       = (const int*)d_in[1];
    const float* eattr    = (const float*)d_in[2];
    const float* ee_w1    = (const float*)d_in[3];
    const float* ee_b1    = (const float*)d_in[4];
    const float* ee_w2    = (const float*)d_in[5];
    const float* ee_b2    = (const float*)d_in[6];
    const float* proj_w   = (const float*)d_in[7];
    const float* proj_b   = (const float*)d_in[8];
    const float* c1_lin   = (const float*)d_in[9];
    const float* c1_asrc  = (const float*)d_in[10];
    const float* c1_adst  = (const float*)d_in[11];
    const float* c1_ledge = (const float*)d_in[12];
    const float* c1_aedge = (const float*)d_in[13];
    const float* c1_bias  = (const float*)d_in[14];
    const float* c2_lin   = (const float*)d_in[15];
    const float* c2_asrc  = (const float*)d_in[16];
    const float* c2_adst  = (const float*)d_in[17];
    const float* c2_ledge = (const float*)d_in[18];
    const float* c2_aedge = (const float*)d_in[19];
    const float* c2_bias  = (const float*)d_in[20];
    const float* n1_g     = (const float*)d_in[21];
    const float* n1_b     = (const float*)d_in[22];
    const float* n2_g     = (const float*)d_in[23];
    const float* n2_b     = (const float*)d_in[24];
    const float* jk_w     = (const float*)d_in[25];
    const float* jk_b     = (const float*)d_in[26];
    const float* cls_w    = (const float*)d_in[27];
    const float* cls_b    = (const float*)d_in[28];
    float* out = (float*)d_out;
    float* ws  = (float*)d_ws;

    // workspace layout (floats)
    const size_t oM   = 0;                 // 32 (padded to 64)
    const size_t oE4  = 64;                // E*4
    const size_t oEX  = oE4 + (size_t)NE * 4;
    const size_t oHC  = oEX + (size_t)NE * 4;   // N*384  (h0 | h1 | h2)
    const size_t oXS  = oHC + (size_t)NN * 384; // N*128  (xs1/xs2, reused as hjk)
    const size_t oAS  = oXS + (size_t)NN * 128;
    const size_t oAD  = oAS + (size_t)NN * 4;
    const size_t oDEN = oAD + (size_t)NN * 4;
    const size_t oAGG = oDEN + (size_t)NN * 4;  // keep adjacent to oDEN for single fill

    float* Mmat  = ws + oM;
    float* e4    = ws + oE4;
    float* exb   = ws + oEX;
    float* hcat  = ws + oHC;
    float* xs    = ws + oXS;
    float* as_b  = ws + oAS;
    float* ad_b  = ws + oAD;
    float* den   = ws + oDEN;
    float* agg   = ws + oAGG;

    const int EB = (NE + 255) / 256;          // 3125
    const int NB = (NN + 255) / 256;          // 196
    const int GB = (NN + 127) / 128;          // 391
    const long long AGGN = (long long)NE * 32;
    const int AB = (int)((AGGN + 255) / 256); // 100000
    const long long FILLN = (long long)NN * 132;
    const int FB = (int)((FILLN + 255) / 256);

    k_prep<<<1, 64, 0, stream>>>(c1_ledge, c1_aedge, c2_ledge, c2_aedge, Mmat);
    k_edge<<<EB, 256, 0, stream>>>(eattr, ee_w1, ee_b1, ee_w2, ee_b2, e4);

    // h0 -> hcat[:,0:128] ; xs1 -> xs
    gemm_nt<<<GB, 256, 0, stream>>>(x, 16, 16, proj_w, proj_b, hcat, 384, NN);
    gemm_nt<<<GB, 256, 0, stream>>>(x, 16, 16, c1_lin, nullptr, xs, 128, NN);

    // ---- conv1
    k_att_reduce<<<NB, 256, 0, stream>>>(xs, c1_asrc, c1_adst, as_b, ad_b);
    k_fill<<<FB, 256, 0, stream>>>(den, 0.f, FILLN);
    k_edge_soft<<<EB, 256, 0, stream>>>(ei, as_b, ad_b, e4, Mmat, exb, den);
    k_agg<<<AB, 256, 0, stream>>>(ei, exb, xs, agg);
    k_epilogue<<<NN / 2, 256, 0, stream>>>(agg, den, c1_bias, hcat, n1_g, n1_b, hcat + 128);

    // ---- conv2 (input h1 = hcat[:,128:256])
    gemm_nt<<<GB, 256, 0, stream>>>(hcat + 128, 384, 128, c2_lin, nullptr, xs, 128, NN);
    k_att_reduce<<<NB, 256, 0, stream>>>(xs, c2_asrc, c2_adst, as_b, ad_b);
    k_fill<<<FB, 256, 0, stream>>>(den, 0.f, FILLN);
    k_edge_soft<<<EB, 256, 0, stream>>>(ei, as_b, ad_b, e4, Mmat + 16, exb, den);
    k_agg<<<AB, 256, 0, stream>>>(ei, exb, xs, agg);
    k_epilogue<<<NN / 2, 256, 0, stream>>>(agg, den, c2_bias, hcat + 128, n2_g, n2_b, hcat + 256);

    // ---- jk projection: hjk = hcat @ jk_w^T + jk_b  (reuse xs buffer)
    gemm_nt<<<GB, 256, 0, stream>>>(hcat, 384, 384, jk_w, jk_b, xs, 128, NN);

    // ---- classifier + log_softmax
    k_final<<<NB, 256, 0, stream>>>(xs, cls_w, cls_b, out);
}

// Round 2
// 749.747 us; speedup vs baseline: 4.4939x; 4.4939x over previous
//
#include <hip/hip_runtime.h>
#include <cstdint>

#define NN 50000
#define NE 800000

// ---------------- tiny precompute: M[h][k] = sum_c lin_edge[(h*32+c)*4+k]*att_edge[h*32+c]
__global__ void k_prep(const float* __restrict__ le1, const float* __restrict__ ae1,
                       const float* __restrict__ le2, const float* __restrict__ ae2,
                       float* __restrict__ M)
{
    int t = threadIdx.x;
    if (t >= 32) return;
    const float* le = (t < 16) ? le1 : le2;
    const float* ae = (t < 16) ? ae1 : ae2;
    int hk = t & 15, h = hk >> 2, k = hk & 3;
    float s = 0.f;
    for (int c = 0; c < 32; ++c)
        s += le[(h * 32 + c) * 4 + k] * ae[h * 32 + c];
    M[t] = s;
}

// ---------------- edge encoder: e4 = W2*relu(W1*ea+b1)+b2  (per edge)
__global__ __launch_bounds__(256) void k_edge(const float* __restrict__ ea,
                                              const float* __restrict__ w1,
                                              const float* __restrict__ b1,
                                              const float* __restrict__ w2,
                                              const float* __restrict__ b2,
                                              float* __restrict__ e4out)
{
    __shared__ float sw1[256], sb1[32], sw2[128], sb2[4];
    int t = threadIdx.x;
    sw1[t] = w1[t];
    if (t < 128) sw2[t] = w2[t];
    if (t < 32)  sb1[t] = b1[t];
    if (t < 4)   sb2[t] = b2[t];
    __syncthreads();
    int e = blockIdx.x * 256 + t;
    if (e >= NE) return;
    float4 x0 = *(const float4*)(ea + (size_t)e * 8);
    float4 x1 = *(const float4*)(ea + (size_t)e * 8 + 4);
    float o0 = sb2[0], o1 = sb2[1], o2 = sb2[2], o3 = sb2[3];
    #pragma unroll
    for (int j = 0; j < 32; ++j) {
        const float* w = sw1 + j * 8;
        float s = sb1[j] + w[0]*x0.x + w[1]*x0.y + w[2]*x0.z + w[3]*x0.w
                         + w[4]*x1.x + w[5]*x1.y + w[6]*x1.z + w[7]*x1.w;
        s = fmaxf(s, 0.f);
        o0 += sw2[0*32+j] * s; o1 += sw2[1*32+j] * s;
        o2 += sw2[2*32+j] * s; o3 += sw2[3*32+j] * s;
    }
    *(float4*)(e4out + (size_t)e * 4) = make_float4(o0, o1, o2, o3);
}

// ---------------- generic fp32 GEMM: C[M,128] = A[M,K] * W[128,K]^T (+bias)
__global__ __launch_bounds__(256) void gemm_nt(const float* __restrict__ A, int lda, int K,
                                               const float* __restrict__ W,
                                               const float* __restrict__ bias,
                                               float* __restrict__ C, int ldc, int M)
{
    __shared__ float As[16][128];
    __shared__ float Ws[16][128];
    int t = threadIdx.x;
    int m0 = blockIdx.x * 128;
    int ty = t >> 4, tx = t & 15;
    float acc[8][8];
    #pragma unroll
    for (int i = 0; i < 8; ++i)
        #pragma unroll
        for (int j = 0; j < 8; ++j) acc[i][j] = 0.f;
    int lr = t >> 1;
    int lk = (t & 1) * 8;
    for (int k0 = 0; k0 < K; k0 += 16) {
        int ar = m0 + lr; if (ar >= M) ar = M - 1;
        const float* ap = A + (size_t)ar * lda + k0 + lk;
        float4 a0 = *(const float4*)ap, a1 = *(const float4*)(ap + 4);
        const float* wp = W + (size_t)lr * K + k0 + lk;
        float4 w0 = *(const float4*)wp, w1 = *(const float4*)(wp + 4);
        As[lk+0][lr]=a0.x; As[lk+1][lr]=a0.y; As[lk+2][lr]=a0.z; As[lk+3][lr]=a0.w;
        As[lk+4][lr]=a1.x; As[lk+5][lr]=a1.y; As[lk+6][lr]=a1.z; As[lk+7][lr]=a1.w;
        Ws[lk+0][lr]=w0.x; Ws[lk+1][lr]=w0.y; Ws[lk+2][lr]=w0.z; Ws[lk+3][lr]=w0.w;
        Ws[lk+4][lr]=w1.x; Ws[lk+5][lr]=w1.y; Ws[lk+6][lr]=w1.z; Ws[lk+7][lr]=w1.w;
        __syncthreads();
        #pragma unroll
        for (int k = 0; k < 16; ++k) {
            float a[8], b[8];
            *(float4*)(a)     = *(const float4*)&As[k][ty * 8];
            *(float4*)(a + 4) = *(const float4*)&As[k][ty * 8 + 4];
            *(float4*)(b)     = *(const float4*)&Ws[k][tx * 8];
            *(float4*)(b + 4) = *(const float4*)&Ws[k][tx * 8 + 4];
            #pragma unroll
            for (int i = 0; i < 8; ++i)
                #pragma unroll
                for (int j = 0; j < 8; ++j)
                    acc[i][j] = fmaf(a[i], b[j], acc[i][j]);
        }
        __syncthreads();
    }
    float bv[8];
    #pragma unroll
    for (int j = 0; j < 8; ++j) bv[j] = bias ? bias[tx * 8 + j] : 0.f;
    #pragma unroll
    for (int i = 0; i < 8; ++i) {
        int r = m0 + ty * 8 + i;
        if (r < M) {
            float* cp = C + (size_t)r * ldc + tx * 8;
            *(float4*)cp       = make_float4(acc[i][0]+bv[0], acc[i][1]+bv[1], acc[i][2]+bv[2], acc[i][3]+bv[3]);
            *(float4*)(cp + 4) = make_float4(acc[i][4]+bv[4], acc[i][5]+bv[5], acc[i][6]+bv[6], acc[i][7]+bv[7]);
        }
    }
}

// ---------------- per-node attention coefficients: as[n,h], ad[n,h]
__global__ __launch_bounds__(256) void k_att_reduce(const float* __restrict__ xs,
                                                    const float* __restrict__ att_src,
                                                    const float* __restrict__ att_dst,
                                                    float* __restrict__ as_out,
                                                    float* __restrict__ ad_out)
{
    __shared__ float ssrc[128], sdst[128];
    int t = threadIdx.x;
    if (t < 128) { ssrc[t] = att_src[t]; sdst[t] = att_dst[t]; }
    __syncthreads();
    int n = blockIdx.x * 256 + t;
    if (n >= NN) return;
    float s[4] = {0,0,0,0}, d[4] = {0,0,0,0};
    const float4* xr = (const float4*)(xs + (size_t)n * 128);
    #pragma unroll
    for (int q = 0; q < 32; ++q) {
        float4 v = xr[q];
        int h = q >> 3;
        const float* aw = ssrc + q * 4;
        const float* dw = sdst + q * 4;
        s[h] += v.x*aw[0] + v.y*aw[1] + v.z*aw[2] + v.w*aw[3];
        d[h] += v.x*dw[0] + v.y*dw[1] + v.z*dw[2] + v.w*dw[3];
    }
    *(float4*)(as_out + (size_t)n * 4) = make_float4(s[0], s[1], s[2], s[3]);
    *(float4*)(ad_out + (size_t)n * 4) = make_float4(d[0], d[1], d[2], d[3]);
}

// ---------------- per-edge: ex = exp(leaky(as[src]+ad[dst]+M*e4))   (no denom atomics)
__global__ __launch_bounds__(256) void k_edge_soft(const int* __restrict__ ei,
                                                   const float* __restrict__ as_in,
                                                   const float* __restrict__ ad_in,
                                                   const float* __restrict__ e4,
                                                   const float* __restrict__ Mm,
                                                   float* __restrict__ ex_out)
{
    __shared__ float sM[16];
    int t = threadIdx.x;
    if (t < 16) sM[t] = Mm[t];
    __syncthreads();
    int e = blockIdx.x * 256 + t;
    if (e >= NE) return;
    int src = ei[e], dst = ei[NE + e];
    float4 s4 = *(const float4*)(as_in + (size_t)src * 4);
    float4 d4 = *(const float4*)(ad_in + (size_t)dst * 4);
    float4 ev = *(const float4*)(e4 + (size_t)e * 4);
    float sa[4] = {s4.x, s4.y, s4.z, s4.w};
    float da[4] = {d4.x, d4.y, d4.z, d4.w};
    float ex[4];
    #pragma unroll
    for (int h = 0; h < 4; ++h) {
        float ae = sM[h*4+0]*ev.x + sM[h*4+1]*ev.y + sM[h*4+2]*ev.z + sM[h*4+3]*ev.w;
        float a = sa[h] + da[h] + ae;
        a = a > 0.f ? a : 0.2f * a;
        ex[h] = expf(a);
    }
    *(float4*)(ex_out + (size_t)e * 4) = make_float4(ex[0], ex[1], ex[2], ex[3]);
}

// ---------------- CSR build ----------------
__global__ void k_zero_int(int* __restrict__ p, int cnt)
{
    int i = blockIdx.x * 256 + threadIdx.x;
    if (i < cnt) p[i] = 0;
}

__global__ __launch_bounds__(256) void k_hist(const int* __restrict__ ei, int* __restrict__ deg)
{
    int e = blockIdx.x * 256 + threadIdx.x;
    if (e < NE) atomicAdd(&deg[ei[NE + e]], 1);
}

// exclusive scan of deg[0..NN) -> off & cursor; off[NN] = total. Single block of 1024.
__global__ __launch_bounds__(1024) void k_scan(const int* __restrict__ deg,
                                               int* __restrict__ off,
                                               int* __restrict__ cursor)
{
    __shared__ int tmp[1024];
    __shared__ int carry;
    int t = threadIdx.x;
    if (t == 0) carry = 0;
    __syncthreads();
    for (int base = 0; base < NN; base += 1024) {
        int i = base + t;
        int v = (i < NN) ? deg[i] : 0;
        tmp[t] = v;
        __syncthreads();
        #pragma unroll
        for (int o = 1; o < 1024; o <<= 1) {
            int add = (t >= o) ? tmp[t - o] : 0;
            __syncthreads();
            tmp[t] += add;
            __syncthreads();
        }
        int excl = tmp[t] - v + carry;
        if (i < NN) { off[i] = excl; cursor[i] = excl; }
        __syncthreads();
        if (t == 0) carry += tmp[1023];
        __syncthreads();
    }
    if (t == 0) off[NN] = carry;
}

__global__ __launch_bounds__(256) void k_scatter(const int* __restrict__ ei,
                                                 int* __restrict__ cursor,
                                                 int2* __restrict__ csr)
{
    int e = blockIdx.x * 256 + threadIdx.x;
    if (e >= NE) return;
    int src = ei[e], dst = ei[NE + e];
    int p = atomicAdd(&cursor[dst], 1);
    csr[p] = make_int2(src, e);
}

// ---------------- fused CSR aggregation + softmax-normalize + bias + ELU + residual + LayerNorm
// one wave per destination node; lane owns channels 2*lane, 2*lane+1
__global__ __launch_bounds__(256) void k_agg_csr(const int* __restrict__ off,
                                                 const int2* __restrict__ csr,
                                                 const float* __restrict__ ex,
                                                 const float* __restrict__ xs,
                                                 const float* __restrict__ bias,
                                                 const float* __restrict__ resid,
                                                 const float* __restrict__ g,
                                                 const float* __restrict__ bln,
                                                 float* __restrict__ outp)
{
    int wave = threadIdx.x >> 6;
    int lane = threadIdx.x & 63;
    int n = blockIdx.x * 4 + wave;
    if (n >= NN) return;
    int i0 = off[n], i1 = off[n + 1];
    int c0 = lane * 2;
    int h = lane >> 4;                       // channel/32
    float a0 = 0.f, a1 = 0.f, den = 0.f;
    for (int i = i0; i < i1; ++i) {
        int2 se = csr[i];                    // (src, e) — wave-uniform load
        float w = ex[(size_t)se.y * 4 + h];
        float2 v = *(const float2*)(xs + (size_t)se.x * 128 + c0);
        a0 = fmaf(v.x, w, a0);
        a1 = fmaf(v.y, w, a1);
        den += w;
    }
    float inv = 1.f / (den + 1e-16f);
    float v0 = a0 * inv + bias[c0];
    float v1 = a1 * inv + bias[c0 + 1];
    v0 = v0 > 0.f ? v0 : (expf(v0) - 1.f);
    v1 = v1 > 0.f ? v1 : (expf(v1) - 1.f);
    const float* rr = resid + (size_t)n * 384 + c0;
    float r0 = v0 + rr[0];
    float r1 = v1 + rr[1];
    float ssum = r0 + r1, ssq = r0 * r0 + r1 * r1;
    #pragma unroll
    for (int o = 1; o < 64; o <<= 1) {
        ssum += __shfl_xor(ssum, o, 64);
        ssq  += __shfl_xor(ssq, o, 64);
    }
    float mu = ssum * (1.f / 128.f);
    float var = ssq * (1.f / 128.f) - mu * mu;
    float rs = rsqrtf(var + 1e-5f);
    float* op = outp + (size_t)n * 384 + c0;
    op[0] = (r0 - mu) * rs * g[c0] + bln[c0];
    op[1] = (r1 - mu) * rs * g[c0 + 1] + bln[c0 + 1];
}

// ---------------- classifier + log_softmax
__global__ __launch_bounds__(256) void k_final(const float* __restrict__ hjk,
                                               const float* __restrict__ cw,
                                               const float* __restrict__ cb,
                                               float* __restrict__ out)
{
    __shared__ float scw[640], scb[5];
    int t = threadIdx.x;
    for (int i = t; i < 640; i += 256) scw[i] = cw[i];
    if (t < 5) scb[t] = cb[t];
    __syncthreads();
    int n = blockIdx.x * 256 + t;
    if (n >= NN) return;
    float acc[5] = {scb[0], scb[1], scb[2], scb[3], scb[4]};
    const float4* hr = (const float4*)(hjk + (size_t)n * 128);
    #pragma unroll
    for (int q = 0; q < 32; ++q) {
        float4 v = hr[q];
        #pragma unroll
        for (int o = 0; o < 5; ++o) {
            const float* w = scw + o * 128 + q * 4;
            acc[o] += v.x*w[0] + v.y*w[1] + v.z*w[2] + v.w*w[3];
        }
    }
    float m = acc[0];
    #pragma unroll
    for (int o = 1; o < 5; ++o) m = fmaxf(m, acc[o]);
    float sum = 0.f;
    #pragma unroll
    for (int o = 0; o < 5; ++o) sum += expf(acc[o] - m);
    float lse = logf(sum) + m;
    float* op = out + (size_t)n * 5;
    #pragma unroll
    for (int o = 0; o < 5; ++o) op[o] = acc[o] - lse;
}

extern "C" void kernel_launch(void* const* d_in, const int* in_sizes, int n_in,
                              void* d_out, int out_size, void* d_ws, size_t ws_size,
                              hipStream_t stream)
{
    (void)in_sizes; (void)n_in; (void)out_size; (void)ws_size;
    const float* x        = (const float*)d_in[0];
    const int*   ei       = (const int*)d_in[1];
    const float* eattr    = (const float*)d_in[2];
    const float* ee_w1    = (const float*)d_in[3];
    const float* ee_b1    = (const float*)d_in[4];
    const float* ee_w2    = (const float*)d_in[5];
    const float* ee_b2    = (const float*)d_in[6];
    const float* proj_w   = (const float*)d_in[7];
    const float* proj_b   = (const float*)d_in[8];
    const float* c1_lin   = (const float*)d_in[9];
    const float* c1_asrc  = (const float*)d_in[10];
    const float* c1_adst  = (const float*)d_in[11];
    const float* c1_ledge = (const float*)d_in[12];
    const float* c1_aedge = (const float*)d_in[13];
    const float* c1_bias  = (const float*)d_in[14];
    const float* c2_lin   = (const float*)d_in[15];
    const float* c2_asrc  = (const float*)d_in[16];
    const float* c2_adst  = (const float*)d_in[17];
    const float* c2_ledge = (const float*)d_in[18];
    const float* c2_aedge = (const float*)d_in[19];
    const float* c2_bias  = (const float*)d_in[20];
    const float* n1_g     = (const float*)d_in[21];
    const float* n1_b     = (const float*)d_in[22];
    const float* n2_g     = (const float*)d_in[23];
    const float* n2_b     = (const float*)d_in[24];
    const float* jk_w     = (const float*)d_in[25];
    const float* jk_b     = (const float*)d_in[26];
    const float* cls_w    = (const float*)d_in[27];
    const float* cls_b    = (const float*)d_in[28];
    float* out = (float*)d_out;
    float* ws  = (float*)d_ws;

    // workspace layout (floats / ints)
    const size_t oM   = 0;                       // 32 (pad 64)
    const size_t oE4  = 64;                      // E*4
    const size_t oEX  = oE4 + (size_t)NE * 4;    // E*4
    const size_t oHC  = oEX + (size_t)NE * 4;    // N*384
    const size_t oXS  = oHC + (size_t)NN * 384;  // N*128
    const size_t oAS  = oXS + (size_t)NN * 128;  // N*4
    const size_t oAD  = oAS + (size_t)NN * 4;    // N*4
    const size_t oDEG = oAD + (size_t)NN * 4;    // NN ints
    const size_t oOFF = oDEG + NN;               // NN+1 ints (+pad)
    const size_t oCUR = oOFF + NN + 64;          // NN ints
    const size_t oCSR = oCUR + NN;               // NE int2 (even-aligned)

    float* Mmat  = ws + oM;
    float* e4    = ws + oE4;
    float* exb   = ws + oEX;
    float* hcat  = ws + oHC;
    float* xs    = ws + oXS;
    float* as_b  = ws + oAS;
    float* ad_b  = ws + oAD;
    int*   deg   = (int*)(ws + oDEG);
    int*   off   = (int*)(ws + oOFF);
    int*   cur   = (int*)(ws + oCUR);
    int2*  csr   = (int2*)(ws + oCSR);

    const int EB = (NE + 255) / 256;          // 3125
    const int NB = (NN + 255) / 256;          // 196
    const int GB = (NN + 127) / 128;          // 391
    const int WB = (NN + 3) / 4;              // 12500 (wave-per-node agg)

    // CSR build (edge_index only; shared by both convs)
    k_zero_int<<<NB, 256, 0, stream>>>(deg, NN);
    k_hist<<<EB, 256, 0, stream>>>(ei, deg);
    k_scan<<<1, 1024, 0, stream>>>(deg, off, cur);
    k_scatter<<<EB, 256, 0, stream>>>(ei, cur, csr);

    k_prep<<<1, 64, 0, stream>>>(c1_ledge, c1_aedge, c2_ledge, c2_aedge, Mmat);
    k_edge<<<EB, 256, 0, stream>>>(eattr, ee_w1, ee_b1, ee_w2, ee_b2, e4);

    // h0 -> hcat[:,0:128] ; xs1 -> xs
    gemm_nt<<<GB, 256, 0, stream>>>(x, 16, 16, proj_w, proj_b, hcat, 384, NN);
    gemm_nt<<<GB, 256, 0, stream>>>(x, 16, 16, c1_lin, nullptr, xs, 128, NN);

    // ---- conv1
    k_att_reduce<<<NB, 256, 0, stream>>>(xs, c1_asrc, c1_adst, as_b, ad_b);
    k_edge_soft<<<EB, 256, 0, stream>>>(ei, as_b, ad_b, e4, Mmat, exb);
    k_agg_csr<<<WB, 256, 0, stream>>>(off, csr, exb, xs, c1_bias, hcat, n1_g, n1_b, hcat + 128);

    // ---- conv2 (input h1 = hcat[:,128:256])
    gemm_nt<<<GB, 256, 0, stream>>>(hcat + 128, 384, 128, c2_lin, nullptr, xs, 128, NN);
    k_att_reduce<<<NB, 256, 0, stream>>>(xs, c2_asrc, c2_adst, as_b, ad_b);
    k_edge_soft<<<EB, 256, 0, stream>>>(ei, as_b, ad_b, e4, Mmat + 16, exb);
    k_agg_csr<<<WB, 256, 0, stream>>>(off, csr, exb, xs, c2_bias, hcat + 128, n2_g, n2_b, hcat + 256);

    // ---- jk projection: hjk = hcat @ jk_w^T + jk_b  (reuse xs buffer)
    gemm_nt<<<GB, 256, 0, stream>>>(hcat, 384, 384, jk_w, jk_b, xs, 128, NN);

    // ---- classifier + log_softmax
    k_final<<<NB, 256, 0, stream>>>(xs, cls_w, cls_b, out);
}

// Round 3
// 568.037 us; speedup vs baseline: 5.9315x; 1.3199x over previous
//
#include <hip/hip_runtime.h>
#include <cstdint>

#define NN 50000
#define NE 800000

using short8  = __attribute__((ext_vector_type(8))) short;
using float4v = __attribute__((ext_vector_type(4))) float;

__device__ __forceinline__ ushort f2bf(float f) {
    uint u = __float_as_uint(f);
    uint r = (u + 0x7fffu + ((u >> 16) & 1u)) >> 16;
    return (ushort)r;
}
__device__ __forceinline__ float bf2f(uint u) {
    return __uint_as_float(u << 16);
}

// ---------------- tiny precompute: M[h][k] = sum_c lin_edge[(h*32+c)*4+k]*att_edge[h*32+c]
__global__ void k_prep(const float* __restrict__ le1, const float* __restrict__ ae1,
                       const float* __restrict__ le2, const float* __restrict__ ae2,
                       float* __restrict__ M)
{
    int t = threadIdx.x;
    if (t >= 32) return;
    const float* le = (t < 16) ? le1 : le2;
    const float* ae = (t < 16) ? ae1 : ae2;
    int hk = t & 15, h = hk >> 2, k = hk & 3;
    float s = 0.f;
    for (int c = 0; c < 32; ++c)
        s += le[(h * 32 + c) * 4 + k] * ae[h * 32 + c];
    M[t] = s;
}

// ---------------- edge encoder: e4 = W2*relu(W1*ea+b1)+b2  (per edge)
__global__ __launch_bounds__(256) void k_edge(const float* __restrict__ ea,
                                              const float* __restrict__ w1,
                                              const float* __restrict__ b1,
                                              const float* __restrict__ w2,
                                              const float* __restrict__ b2,
                                              float* __restrict__ e4out)
{
    __shared__ float sw1[256], sb1[32], sw2[128], sb2[4];
    int t = threadIdx.x;
    sw1[t] = w1[t];
    if (t < 128) sw2[t] = w2[t];
    if (t < 32)  sb1[t] = b1[t];
    if (t < 4)   sb2[t] = b2[t];
    __syncthreads();
    int e = blockIdx.x * 256 + t;
    if (e >= NE) return;
    float4 x0 = *(const float4*)(ea + (size_t)e * 8);
    float4 x1 = *(const float4*)(ea + (size_t)e * 8 + 4);
    float o0 = sb2[0], o1 = sb2[1], o2 = sb2[2], o3 = sb2[3];
    #pragma unroll
    for (int j = 0; j < 32; ++j) {
        const float* w = sw1 + j * 8;
        float s = sb1[j] + w[0]*x0.x + w[1]*x0.y + w[2]*x0.z + w[3]*x0.w
                         + w[4]*x1.x + w[5]*x1.y + w[6]*x1.z + w[7]*x1.w;
        s = fmaxf(s, 0.f);
        o0 += sw2[0*32+j] * s; o1 += sw2[1*32+j] * s;
        o2 += sw2[2*32+j] * s; o3 += sw2[3*32+j] * s;
    }
    *(float4*)(e4out + (size_t)e * 4) = make_float4(o0, o1, o2, o3);
}

// ---------------- convert fp32 -> bf16 with K padding: dst[r][c<ks]=src, else 0
__global__ __launch_bounds__(256) void k_cvt_pad(const float* __restrict__ src,
                                                 ushort* __restrict__ dst,
                                                 int rows, int ks, int kd)
{
    int i = blockIdx.x * 256 + threadIdx.x;
    if (i >= rows * kd) return;
    int r = i / kd, c = i - r * kd;
    dst[i] = (c < ks) ? f2bf(src[(size_t)r * ks + c]) : (ushort)0;
}

// ---------------- bf16 MFMA GEMM: C[M,128] = A[M,K]*W[128,K]^T (+bias); out fp32 and/or bf16
// block = 4 waves; wave does 32 rows x 128 cols; 16x16x32 mfma, no LDS (B hot in L1/L2)
__global__ __launch_bounds__(256) void gemm_bf16(const ushort* __restrict__ A, int lda, int K,
                                                 const ushort* __restrict__ W, int ldw,
                                                 const float* __restrict__ bias,
                                                 float* __restrict__ C, int ldc,
                                                 ushort* __restrict__ Cb, int ldcb, int M)
{
    int t = threadIdx.x;
    int wv = t >> 6, lane = t & 63;
    int quad = lane >> 4, r16 = lane & 15;
    int m0 = blockIdx.x * 128 + wv * 32;
    float4v acc[2][8];
    #pragma unroll
    for (int i = 0; i < 2; ++i)
        #pragma unroll
        for (int j = 0; j < 8; ++j) acc[i][j] = (float4v){0.f, 0.f, 0.f, 0.f};
    int ar0 = m0 + r16;      if (ar0 >= M) ar0 = M - 1;
    int ar1 = m0 + 16 + r16; if (ar1 >= M) ar1 = M - 1;
    const ushort* a0p = A + (size_t)ar0 * lda + quad * 8;
    const ushort* a1p = A + (size_t)ar1 * lda + quad * 8;
    const ushort* wp  = W + (size_t)r16 * ldw + quad * 8;
    for (int k0 = 0; k0 < K; k0 += 32) {
        short8 a0 = *(const short8*)(a0p + k0);
        short8 a1 = *(const short8*)(a1p + k0);
        #pragma unroll
        for (int nt = 0; nt < 8; ++nt) {
            short8 b = *(const short8*)(wp + (size_t)(nt * 16) * ldw + k0);
            acc[0][nt] = __builtin_amdgcn_mfma_f32_16x16x32_bf16(a0, b, acc[0][nt], 0, 0, 0);
            acc[1][nt] = __builtin_amdgcn_mfma_f32_16x16x32_bf16(a1, b, acc[1][nt], 0, 0, 0);
        }
    }
    #pragma unroll
    for (int rt = 0; rt < 2; ++rt) {
        #pragma unroll
        for (int nt = 0; nt < 8; ++nt) {
            int col = nt * 16 + r16;
            float bv = bias ? bias[col] : 0.f;
            #pragma unroll
            for (int r = 0; r < 4; ++r) {
                int row = m0 + rt * 16 + quad * 4 + r;
                if (row < M) {
                    float v = acc[rt][nt][r] + bv;
                    if (C)  C[(size_t)row * ldc + col] = v;
                    if (Cb) Cb[(size_t)row * ldcb + col] = f2bf(v);
                }
            }
        }
    }
}

// ---------------- per-node attention coefficients from bf16 xs
__global__ __launch_bounds__(256) void k_att_reduce(const ushort* __restrict__ xs,
                                                    const float* __restrict__ att_src,
                                                    const float* __restrict__ att_dst,
                                                    float* __restrict__ as_out,
                                                    float* __restrict__ ad_out)
{
    __shared__ float ssrc[128], sdst[128];
    int t = threadIdx.x;
    if (t < 128) { ssrc[t] = att_src[t]; sdst[t] = att_dst[t]; }
    __syncthreads();
    int n = blockIdx.x * 256 + t;
    if (n >= NN) return;
    float s[4] = {0,0,0,0}, d[4] = {0,0,0,0};
    const uint2* xr = (const uint2*)(xs + (size_t)n * 128);
    #pragma unroll
    for (int q = 0; q < 32; ++q) {
        uint2 p = xr[q];
        float v0 = bf2f(p.x & 0xffffu), v1 = bf2f(p.x >> 16);
        float v2 = bf2f(p.y & 0xffffu), v3 = bf2f(p.y >> 16);
        int h = q >> 3;
        const float* aw = ssrc + q * 4;
        const float* dw = sdst + q * 4;
        s[h] += v0*aw[0] + v1*aw[1] + v2*aw[2] + v3*aw[3];
        d[h] += v0*dw[0] + v1*dw[1] + v2*dw[2] + v3*dw[3];
    }
    *(float4*)(as_out + (size_t)n * 4) = make_float4(s[0], s[1], s[2], s[3]);
    *(float4*)(ad_out + (size_t)n * 4) = make_float4(d[0], d[1], d[2], d[3]);
}

// ---------------- per-edge: ex = exp(leaky(as[src]+ad[dst]+M*e4))
__global__ __launch_bounds__(256) void k_edge_soft(const int* __restrict__ ei,
                                                   const float* __restrict__ as_in,
                                                   const float* __restrict__ ad_in,
                                                   const float* __restrict__ e4,
                                                   const float* __restrict__ Mm,
                                                   float* __restrict__ ex_out)
{
    __shared__ float sM[16];
    int t = threadIdx.x;
    if (t < 16) sM[t] = Mm[t];
    __syncthreads();
    int e = blockIdx.x * 256 + t;
    if (e >= NE) return;
    int src = ei[e], dst = ei[NE + e];
    float4 s4 = *(const float4*)(as_in + (size_t)src * 4);
    float4 d4 = *(const float4*)(ad_in + (size_t)dst * 4);
    float4 ev = *(const float4*)(e4 + (size_t)e * 4);
    float sa[4] = {s4.x, s4.y, s4.z, s4.w};
    float da[4] = {d4.x, d4.y, d4.z, d4.w};
    float ex[4];
    #pragma unroll
    for (int h = 0; h < 4; ++h) {
        float ae = sM[h*4+0]*ev.x + sM[h*4+1]*ev.y + sM[h*4+2]*ev.z + sM[h*4+3]*ev.w;
        float a = sa[h] + da[h] + ae;
        a = a > 0.f ? a : 0.2f * a;
        ex[h] = expf(a);
    }
    *(float4*)(ex_out + (size_t)e * 4) = make_float4(ex[0], ex[1], ex[2], ex[3]);
}

// ---------------- CSR build ----------------
__global__ void k_zero_int(int* __restrict__ p, int cnt)
{
    int i = blockIdx.x * 256 + threadIdx.x;
    if (i < cnt) p[i] = 0;
}

__global__ __launch_bounds__(256) void k_hist(const int* __restrict__ ei, int* __restrict__ deg)
{
    int e = blockIdx.x * 256 + threadIdx.x;
    if (e < NE) atomicAdd(&deg[ei[NE + e]], 1);
}

// parallel scan: per-block exclusive scan + block sums
__global__ __launch_bounds__(256) void k_scan_blk(const int* __restrict__ deg,
                                                  int* __restrict__ loc,
                                                  int* __restrict__ bsum)
{
    __shared__ int tmp[256];
    int t = threadIdx.x;
    int i = blockIdx.x * 256 + t;
    int v = (i < NN) ? deg[i] : 0;
    tmp[t] = v;
    __syncthreads();
    #pragma unroll
    for (int o = 1; o < 256; o <<= 1) {
        int add = (t >= o) ? tmp[t - o] : 0;
        __syncthreads();
        tmp[t] += add;
        __syncthreads();
    }
    if (i < NN) loc[i] = tmp[t] - v;
    if (t == 255) bsum[blockIdx.x] = tmp[255];
}

__global__ __launch_bounds__(256) void k_scan_top(const int* __restrict__ bsum,
                                                  int* __restrict__ bcarry,
                                                  int* __restrict__ total_out, int nb)
{
    __shared__ int tmp[256];
    int t = threadIdx.x;
    int v = (t < nb) ? bsum[t] : 0;
    tmp[t] = v;
    __syncthreads();
    #pragma unroll
    for (int o = 1; o < 256; o <<= 1) {
        int add = (t >= o) ? tmp[t - o] : 0;
        __syncthreads();
        tmp[t] += add;
        __syncthreads();
    }
    if (t < nb) bcarry[t] = tmp[t] - v;
    if (t == 255) *total_out = tmp[255];
}

__global__ __launch_bounds__(256) void k_scan_add(const int* __restrict__ loc,
                                                  const int* __restrict__ bcarry,
                                                  int* __restrict__ off,
                                                  int* __restrict__ cur)
{
    int i = blockIdx.x * 256 + threadIdx.x;
    if (i < NN) {
        int o = loc[i] + bcarry[blockIdx.x];
        off[i] = o;
        cur[i] = o;
    }
}

__global__ __launch_bounds__(256) void k_scatter(const int* __restrict__ ei,
                                                 int* __restrict__ cursor,
                                                 int2* __restrict__ csr)
{
    int e = blockIdx.x * 256 + threadIdx.x;
    if (e >= NE) return;
    int src = ei[e], dst = ei[NE + e];
    int p = atomicAdd(&cursor[dst], 1);
    csr[p] = make_int2(src, e);
}

// ---------------- fused CSR aggregation + normalize + bias + ELU + residual(bf16) + LN -> bf16
__global__ __launch_bounds__(256) void k_agg_csr(const int* __restrict__ off,
                                                 const int2* __restrict__ csr,
                                                 const float* __restrict__ ex,
                                                 const ushort* __restrict__ xs,
                                                 const float* __restrict__ bias,
                                                 const ushort* __restrict__ residb,
                                                 const float* __restrict__ g,
                                                 const float* __restrict__ bln,
                                                 ushort* __restrict__ outb)
{
    int wave = threadIdx.x >> 6;
    int lane = threadIdx.x & 63;
    int n = blockIdx.x * 4 + wave;
    if (n >= NN) return;
    int i0 = off[n], i1 = off[n + 1];
    int c0 = lane * 2;
    int h = lane >> 4;
    float a0 = 0.f, a1 = 0.f, den = 0.f;
    for (int i = i0; i < i1; ++i) {
        int2 se = csr[i];
        float w = ex[(size_t)se.y * 4 + h];
        uint p = *(const uint*)(xs + (size_t)se.x * 128 + c0);
        a0 = fmaf(bf2f(p & 0xffffu), w, a0);
        a1 = fmaf(bf2f(p >> 16), w, a1);
        den += w;
    }
    float inv = 1.f / (den + 1e-16f);
    float v0 = a0 * inv + bias[c0];
    float v1 = a1 * inv + bias[c0 + 1];
    v0 = v0 > 0.f ? v0 : (expf(v0) - 1.f);
    v1 = v1 > 0.f ? v1 : (expf(v1) - 1.f);
    uint rp = *(const uint*)(residb + (size_t)n * 384 + c0);
    float r0 = v0 + bf2f(rp & 0xffffu);
    float r1 = v1 + bf2f(rp >> 16);
    float ssum = r0 + r1, ssq = r0 * r0 + r1 * r1;
    #pragma unroll
    for (int o = 1; o < 64; o <<= 1) {
        ssum += __shfl_xor(ssum, o, 64);
        ssq  += __shfl_xor(ssq, o, 64);
    }
    float mu = ssum * (1.f / 128.f);
    float var = ssq * (1.f / 128.f) - mu * mu;
    float rs = rsqrtf(var + 1e-5f);
    float o0 = (r0 - mu) * rs * g[c0] + bln[c0];
    float o1 = (r1 - mu) * rs * g[c0 + 1] + bln[c0 + 1];
    uint pk = (uint)f2bf(o0) | ((uint)f2bf(o1) << 16);
    *(uint*)(outb + (size_t)n * 384 + c0) = pk;
}

// ---------------- classifier + log_softmax (fp32 hjk)
__global__ __launch_bounds__(256) void k_final(const float* __restrict__ hjk,
                                               const float* __restrict__ cw,
                                               const float* __restrict__ cb,
                                               float* __restrict__ out)
{
    __shared__ float scw[640], scb[5];
    int t = threadIdx.x;
    for (int i = t; i < 640; i += 256) scw[i] = cw[i];
    if (t < 5) scb[t] = cb[t];
    __syncthreads();
    int n = blockIdx.x * 256 + t;
    if (n >= NN) return;
    float acc[5] = {scb[0], scb[1], scb[2], scb[3], scb[4]};
    const float4* hr = (const float4*)(hjk + (size_t)n * 128);
    #pragma unroll
    for (int q = 0; q < 32; ++q) {
        float4 v = hr[q];
        #pragma unroll
        for (int o = 0; o < 5; ++o) {
            const float* w = scw + o * 128 + q * 4;
            acc[o] += v.x*w[0] + v.y*w[1] + v.z*w[2] + v.w*w[3];
        }
    }
    float m = acc[0];
    #pragma unroll
    for (int o = 1; o < 5; ++o) m = fmaxf(m, acc[o]);
    float sum = 0.f;
    #pragma unroll
    for (int o = 0; o < 5; ++o) sum += expf(acc[o] - m);
    float lse = logf(sum) + m;
    float* op = out + (size_t)n * 5;
    #pragma unroll
    for (int o = 0; o < 5; ++o) op[o] = acc[o] - lse;
}

extern "C" void kernel_launch(void* const* d_in, const int* in_sizes, int n_in,
                              void* d_out, int out_size, void* d_ws, size_t ws_size,
                              hipStream_t stream)
{
    (void)in_sizes; (void)n_in; (void)out_size; (void)ws_size;
    const float* x        = (const float*)d_in[0];
    const int*   ei       = (const int*)d_in[1];
    const float* eattr    = (const float*)d_in[2];
    const float* ee_w1    = (const float*)d_in[3];
    const float* ee_b1    = (const float*)d_in[4];
    const float* ee_w2    = (const float*)d_in[5];
    const float* ee_b2    = (const float*)d_in[6];
    const float* proj_w   = (const float*)d_in[7];
    const float* proj_b   = (const float*)d_in[8];
    const float* c1_lin   = (const float*)d_in[9];
    const float* c1_asrc  = (const float*)d_in[10];
    const float* c1_adst  = (const float*)d_in[11];
    const float* c1_ledge = (const float*)d_in[12];
    const float* c1_aedge = (const float*)d_in[13];
    const float* c1_bias  = (const float*)d_in[14];
    const float* c2_lin   = (const float*)d_in[15];
    const float* c2_asrc  = (const float*)d_in[16];
    const float* c2_adst  = (const float*)d_in[17];
    const float* c2_ledge = (const float*)d_in[18];
    const float* c2_aedge = (const float*)d_in[19];
    const float* c2_bias  = (const float*)d_in[20];
    const float* n1_g     = (const float*)d_in[21];
    const float* n1_b     = (const float*)d_in[22];
    const float* n2_g     = (const float*)d_in[23];
    const float* n2_b     = (const float*)d_in[24];
    const float* jk_w     = (const float*)d_in[25];
    const float* jk_b     = (const float*)d_in[26];
    const float* cls_w    = (const float*)d_in[27];
    const float* cls_b    = (const float*)d_in[28];
    float* out = (float*)d_out;
    float* ws  = (float*)d_ws;

    // ---- workspace layout (float-element offsets; all 16B-aligned)
    const size_t oM  = 0;                          // 64 f
    const size_t oE4 = 64;                         // NE*4 f   } together also hjk fp32 (NN*128 f = 6.4M)
    const size_t oEX = oE4 + (size_t)NE * 4;       // NE*4 f   }
    const size_t oHB = oEX + (size_t)NE * 4;       // hcatb bf16 NN*384 us = NN*192 f
    const size_t oXS = oHB + (size_t)NN * 192;     // xs bf16 NN*128 us = NN*64 f
    const size_t oXP = oXS + (size_t)NN * 64;      // xpad bf16 NN*32 us = NN*16 f
    const size_t oWB = oXP + (size_t)NN * 16;      // weights bf16: 73728 us = 36864 f (+pad 16)
    const size_t oAS = oWB + 36880;                // NN*4 f
    const size_t oAD = oAS + (size_t)NN * 4;       // NN*4 f
    const size_t oI  = oAD + (size_t)NN * 4;       // int region

    float*  Mmat  = ws + oM;
    float*  e4    = ws + oE4;
    float*  hjk   = ws + oE4;                      // alias: e4+ex dead before jk GEMM
    float*  exb   = ws + oEX;
    ushort* hcatb = (ushort*)(ws + oHB);
    ushort* xs    = (ushort*)(ws + oXS);
    ushort* xpad  = (ushort*)(ws + oXP);
    ushort* wb    = (ushort*)(ws + oWB);
    ushort* pwb   = wb;                            // 128x32
    ushort* c1b   = wb + 4096;                     // 128x32
    ushort* c2b   = wb + 8192;                     // 128x128
    ushort* jkb   = wb + 24576;                    // 128x384
    float*  as_b  = ws + oAS;
    float*  ad_b  = ws + oAD;
    int*    ip    = (int*)(ws + oI);
    int*    deg   = ip;                            // NN
    int*    loc   = ip + NN;                       // NN
    int*    off   = ip + 2 * NN;                   // NN+16
    int*    cur   = ip + 3 * NN + 16;              // NN
    int*    bsum  = ip + 4 * NN + 16;              // 256
    int*    bcar  = ip + 4 * NN + 272;             // 256
    int2*   csr   = (int2*)(ip + 4 * NN + 528);    // NE int2 (8B-aligned)

    const int EB = (NE + 255) / 256;          // 3125
    const int NB = (NN + 255) / 256;          // 196
    const int GB = (NN + 127) / 128;          // 391
    const int WB2 = (NN + 3) / 4;             // 12500

    // ---- CSR build
    k_zero_int<<<NB, 256, 0, stream>>>(deg, NN);
    k_hist<<<EB, 256, 0, stream>>>(ei, deg);
    k_scan_blk<<<NB, 256, 0, stream>>>(deg, loc, bsum);
    k_scan_top<<<1, 256, 0, stream>>>(bsum, bcar, off + NN, NB);
    k_scan_add<<<NB, 256, 0, stream>>>(loc, bcar, off, cur);
    k_scatter<<<EB, 256, 0, stream>>>(ei, cur, csr);

    // ---- small precomputes + weight conversion
    k_prep<<<1, 64, 0, stream>>>(c1_ledge, c1_aedge, c2_ledge, c2_aedge, Mmat);
    k_edge<<<EB, 256, 0, stream>>>(eattr, ee_w1, ee_b1, ee_w2, ee_b2, e4);
    k_cvt_pad<<<(NN*32 + 255)/256, 256, 0, stream>>>(x, xpad, NN, 16, 32);
    k_cvt_pad<<<16, 256, 0, stream>>>(proj_w, pwb, 128, 16, 32);
    k_cvt_pad<<<16, 256, 0, stream>>>(c1_lin, c1b, 128, 16, 32);
    k_cvt_pad<<<64, 256, 0, stream>>>(c2_lin, c2b, 128, 128, 128);
    k_cvt_pad<<<192, 256, 0, stream>>>(jk_w, jkb, 128, 384, 384);

    // ---- h0 (bf16 into hcatb col 0) ; xs1
    gemm_bf16<<<GB, 256, 0, stream>>>(xpad, 32, 32, pwb, 32, proj_b, nullptr, 0, hcatb, 384, NN);
    gemm_bf16<<<GB, 256, 0, stream>>>(xpad, 32, 32, c1b, 32, nullptr, nullptr, 0, xs, 128, NN);

    // ---- conv1
    k_att_reduce<<<NB, 256, 0, stream>>>(xs, c1_asrc, c1_adst, as_b, ad_b);
    k_edge_soft<<<EB, 256, 0, stream>>>(ei, as_b, ad_b, e4, Mmat, exb);
    k_agg_csr<<<WB2, 256, 0, stream>>>(off, csr, exb, xs, c1_bias, hcatb, n1_g, n1_b, hcatb + 128);

    // ---- conv2 (A = h1 bf16 at hcatb col 128)
    gemm_bf16<<<GB, 256, 0, stream>>>(hcatb + 128, 384, 128, c2b, 128, nullptr, nullptr, 0, xs, 128, NN);
    k_att_reduce<<<NB, 256, 0, stream>>>(xs, c2_asrc, c2_adst, as_b, ad_b);
    k_edge_soft<<<EB, 256, 0, stream>>>(ei, as_b, ad_b, e4, Mmat + 16, exb);
    k_agg_csr<<<WB2, 256, 0, stream>>>(off, csr, exb, xs, c2_bias, hcatb + 128, n2_g, n2_b, hcatb + 256);

    // ---- jk projection: hjk(fp32) = hcatb[N,384] @ jk_w^T + jk_b   (aliases dead e4/ex)
    gemm_bf16<<<GB, 256, 0, stream>>>(hcatb, 384, 384, jkb, 384, jk_b, hjk, 128, nullptr, 0, NN);

    // ---- classifier + log_softmax
    k_final<<<NB, 256, 0, stream>>>(hjk, cls_w, cls_b, out);
}

// Round 4
// 427.488 us; speedup vs baseline: 7.8816x; 1.3288x over previous
//
#include <hip/hip_runtime.h>
#include <cstdint>

#define NN 50000
#define NE 800000

using short8  = __attribute__((ext_vector_type(8))) short;
using float4v = __attribute__((ext_vector_type(4))) float;

__device__ __forceinline__ ushort f2bf(float f) {
    uint u = __float_as_uint(f);
    uint r = (u + 0x7fffu + ((u >> 16) & 1u)) >> 16;
    return (ushort)r;
}
__device__ __forceinline__ float bf2f(uint u) {
    return __uint_as_float(u << 16);
}

// ---------------- fused tiny precompute:
//  M[h][k] (2 convs, 32 vals), CW[5,384]=cls_w@jk_w, cbp[5]=cls_w@jk_b+cls_b
__global__ __launch_bounds__(256) void k_prep2(const float* __restrict__ le1, const float* __restrict__ ae1,
                                               const float* __restrict__ le2, const float* __restrict__ ae2,
                                               const float* __restrict__ jkw, const float* __restrict__ jkb,
                                               const float* __restrict__ clw, const float* __restrict__ clb,
                                               float* __restrict__ M, float* __restrict__ CW,
                                               float* __restrict__ cbp)
{
    int idx = blockIdx.x * 256 + threadIdx.x;
    if (idx < 32) {
        const float* le = (idx < 16) ? le1 : le2;
        const float* ae = (idx < 16) ? ae1 : ae2;
        int hk = idx & 15, h = hk >> 2, k = hk & 3;
        float s = 0.f;
        for (int c = 0; c < 32; ++c)
            s += le[(h * 32 + c) * 4 + k] * ae[h * 32 + c];
        M[idx] = s;
    } else if (idx < 32 + 1920) {
        int o = idx - 32;
        int r = o / 384, c = o - r * 384;
        float s = 0.f;
        for (int k = 0; k < 128; ++k)
            s += clw[r * 128 + k] * jkw[(size_t)k * 384 + c];
        CW[o] = s;
    } else if (idx < 32 + 1920 + 5) {
        int r = idx - 1952;
        float s = clb[r];
        for (int k = 0; k < 128; ++k)
            s += clw[r * 128 + k] * jkb[k];
        cbp[r] = s;
    }
}

// ---------------- CSR build ----------------
__global__ void k_zero_int(int* __restrict__ p, int cnt)
{
    int i = blockIdx.x * 256 + threadIdx.x;
    if (i < cnt) p[i] = 0;
}

__global__ __launch_bounds__(256) void k_hist(const int* __restrict__ ei, int* __restrict__ deg)
{
    int e = blockIdx.x * 256 + threadIdx.x;
    if (e < NE) atomicAdd(&deg[ei[NE + e]], 1);
}

__global__ __launch_bounds__(256) void k_scan_blk(const int* __restrict__ deg,
                                                  int* __restrict__ loc,
                                                  int* __restrict__ bsum)
{
    __shared__ int tmp[256];
    int t = threadIdx.x;
    int i = blockIdx.x * 256 + t;
    int v = (i < NN) ? deg[i] : 0;
    tmp[t] = v;
    __syncthreads();
    #pragma unroll
    for (int o = 1; o < 256; o <<= 1) {
        int add = (t >= o) ? tmp[t - o] : 0;
        __syncthreads();
        tmp[t] += add;
        __syncthreads();
    }
    if (i < NN) loc[i] = tmp[t] - v;
    if (t == 255) bsum[blockIdx.x] = tmp[255];
}

__global__ __launch_bounds__(256) void k_scan_top(const int* __restrict__ bsum,
                                                  int* __restrict__ bcarry,
                                                  int* __restrict__ total_out, int nb)
{
    __shared__ int tmp[256];
    int t = threadIdx.x;
    int v = (t < nb) ? bsum[t] : 0;
    tmp[t] = v;
    __syncthreads();
    #pragma unroll
    for (int o = 1; o < 256; o <<= 1) {
        int add = (t >= o) ? tmp[t - o] : 0;
        __syncthreads();
        tmp[t] += add;
        __syncthreads();
    }
    if (t < nb) bcarry[t] = tmp[t] - v;
    if (t == 255) *total_out = tmp[255];
}

__global__ __launch_bounds__(256) void k_scan_add(const int* __restrict__ loc,
                                                  const int* __restrict__ bcarry,
                                                  int* __restrict__ off,
                                                  int* __restrict__ cur)
{
    int i = blockIdx.x * 256 + threadIdx.x;
    if (i < NN) {
        int o = loc[i] + bcarry[blockIdx.x];
        off[i] = o;
        cur[i] = o;
    }
}

// ---------------- fused edge encoder MLP + scatter into CSR order
__global__ __launch_bounds__(256) void k_edge_scatter(const float* __restrict__ ea,
                                                      const float* __restrict__ w1,
                                                      const float* __restrict__ b1,
                                                      const float* __restrict__ w2,
                                                      const float* __restrict__ b2,
                                                      const int* __restrict__ ei,
                                                      int* __restrict__ cursor,
                                                      int* __restrict__ csrs,
                                                      float4* __restrict__ e4c)
{
    __shared__ float sw1[256], sb1[32], sw2[128], sb2[4];
    int t = threadIdx.x;
    sw1[t] = w1[t];
    if (t < 128) sw2[t] = w2[t];
    if (t < 32)  sb1[t] = b1[t];
    if (t < 4)   sb2[t] = b2[t];
    __syncthreads();
    int e = blockIdx.x * 256 + t;
    if (e >= NE) return;
    float4 x0 = *(const float4*)(ea + (size_t)e * 8);
    float4 x1 = *(const float4*)(ea + (size_t)e * 8 + 4);
    float o0 = sb2[0], o1 = sb2[1], o2 = sb2[2], o3 = sb2[3];
    #pragma unroll
    for (int j = 0; j < 32; ++j) {
        const float* w = sw1 + j * 8;
        float s = sb1[j] + w[0]*x0.x + w[1]*x0.y + w[2]*x0.z + w[3]*x0.w
                         + w[4]*x1.x + w[5]*x1.y + w[6]*x1.z + w[7]*x1.w;
        s = fmaxf(s, 0.f);
        o0 += sw2[0*32+j] * s; o1 += sw2[1*32+j] * s;
        o2 += sw2[2*32+j] * s; o3 += sw2[3*32+j] * s;
    }
    int src = ei[e], dst = ei[NE + e];
    int p = atomicAdd(&cursor[dst], 1);
    csrs[p] = src;
    e4c[p] = make_float4(o0, o1, o2, o3);
}

// ---------------- convert fp32 -> bf16 with K padding
__global__ __launch_bounds__(256) void k_cvt_pad(const float* __restrict__ src,
                                                 ushort* __restrict__ dst,
                                                 int rows, int ks, int kd)
{
    int i = blockIdx.x * 256 + threadIdx.x;
    if (i >= rows * kd) return;
    int r = i / kd, c = i - r * kd;
    dst[i] = (c < ks) ? f2bf(src[(size_t)r * ks + c]) : (ushort)0;
}

// ---------------- bf16 MFMA GEMM: Cb[M,128] = A[M,K]*W[128,K]^T (+bias), bf16 out
__global__ __launch_bounds__(256) void gemm_bf16(const ushort* __restrict__ A, int lda, int K,
                                                 const ushort* __restrict__ W, int ldw,
                                                 const float* __restrict__ bias,
                                                 ushort* __restrict__ Cb, int ldcb, int M)
{
    int t = threadIdx.x;
    int wv = t >> 6, lane = t & 63;
    int quad = lane >> 4, r16 = lane & 15;
    int m0 = blockIdx.x * 128 + wv * 32;
    float4v acc[2][8];
    #pragma unroll
    for (int i = 0; i < 2; ++i)
        #pragma unroll
        for (int j = 0; j < 8; ++j) acc[i][j] = (float4v){0.f, 0.f, 0.f, 0.f};
    int ar0 = m0 + r16;      if (ar0 >= M) ar0 = M - 1;
    int ar1 = m0 + 16 + r16; if (ar1 >= M) ar1 = M - 1;
    const ushort* a0p = A + (size_t)ar0 * lda + quad * 8;
    const ushort* a1p = A + (size_t)ar1 * lda + quad * 8;
    const ushort* wp  = W + (size_t)r16 * ldw + quad * 8;
    for (int k0 = 0; k0 < K; k0 += 32) {
        short8 a0 = *(const short8*)(a0p + k0);
        short8 a1 = *(const short8*)(a1p + k0);
        #pragma unroll
        for (int nt = 0; nt < 8; ++nt) {
            short8 b = *(const short8*)(wp + (size_t)(nt * 16) * ldw + k0);
            acc[0][nt] = __builtin_amdgcn_mfma_f32_16x16x32_bf16(a0, b, acc[0][nt], 0, 0, 0);
            acc[1][nt] = __builtin_amdgcn_mfma_f32_16x16x32_bf16(a1, b, acc[1][nt], 0, 0, 0);
        }
    }
    #pragma unroll
    for (int rt = 0; rt < 2; ++rt) {
        #pragma unroll
        for (int nt = 0; nt < 8; ++nt) {
            int col = nt * 16 + r16;
            float bv = bias ? bias[col] : 0.f;
            #pragma unroll
            for (int r = 0; r < 4; ++r) {
                int row = m0 + rt * 16 + quad * 4 + r;
                if (row < M)
                    Cb[(size_t)row * ldcb + col] = f2bf(acc[rt][nt][r] + bv);
            }
        }
    }
}

// ---------------- per-node attention coefficients from bf16 xs
__global__ __launch_bounds__(256) void k_att_reduce(const ushort* __restrict__ xs,
                                                    const float* __restrict__ att_src,
                                                    const float* __restrict__ att_dst,
                                                    float* __restrict__ as_out,
                                                    float* __restrict__ ad_out)
{
    __shared__ float ssrc[128], sdst[128];
    int t = threadIdx.x;
    if (t < 128) { ssrc[t] = att_src[t]; sdst[t] = att_dst[t]; }
    __syncthreads();
    int n = blockIdx.x * 256 + t;
    if (n >= NN) return;
    float s[4] = {0,0,0,0}, d[4] = {0,0,0,0};
    const uint2* xr = (const uint2*)(xs + (size_t)n * 128);
    #pragma unroll
    for (int q = 0; q < 32; ++q) {
        uint2 p = xr[q];
        float v0 = bf2f(p.x & 0xffffu), v1 = bf2f(p.x >> 16);
        float v2 = bf2f(p.y & 0xffffu), v3 = bf2f(p.y >> 16);
        int h = q >> 3;
        const float* aw = ssrc + q * 4;
        const float* dw = sdst + q * 4;
        s[h] += v0*aw[0] + v1*aw[1] + v2*aw[2] + v3*aw[3];
        d[h] += v0*dw[0] + v1*dw[1] + v2*dw[2] + v3*dw[3];
    }
    *(float4*)(as_out + (size_t)n * 4) = make_float4(s[0], s[1], s[2], s[3]);
    *(float4*)(ad_out + (size_t)n * 4) = make_float4(d[0], d[1], d[2], d[3]);
}

// ---------------- fused: CSR gather + inline alpha(exp) + aggregate + normalize
//                  + bias + ELU + residual(bf16) + LayerNorm -> bf16
// wave per node; lane owns channels 2*lane,2*lane+1; 4-wide unrolled edge loop
__global__ __launch_bounds__(256) void k_agg2(const int* __restrict__ off,
                                              const int* __restrict__ csrs,
                                              const float4* __restrict__ e4c,
                                              const float* __restrict__ as_in,
                                              const float* __restrict__ ad_in,
                                              const float* __restrict__ Mm,
                                              const ushort* __restrict__ xs,
                                              const float* __restrict__ bias,
                                              const ushort* __restrict__ residb,
                                              const float* __restrict__ g,
                                              const float* __restrict__ bln,
                                              ushort* __restrict__ outb)
{
    int wave = threadIdx.x >> 6;
    int lane = threadIdx.x & 63;
    int n = blockIdx.x * 4 + wave;
    if (n >= NN) return;
    int i0 = off[n], i1 = off[n + 1];
    int c0 = lane * 2;
    int h = lane >> 4;
    float m0 = Mm[h*4+0], m1 = Mm[h*4+1], m2 = Mm[h*4+2], m3 = Mm[h*4+3];
    float adh = ad_in[(size_t)n * 4 + h];
    float a0 = 0.f, a1 = 0.f, den = 0.f;
    int i = i0;
    for (; i + 4 <= i1; i += 4) {
        int s0 = csrs[i], s1 = csrs[i+1], s2 = csrs[i+2], s3 = csrs[i+3];
        float4 e0 = e4c[i], e1 = e4c[i+1], e2 = e4c[i+2], e3 = e4c[i+3];
        float y0 = as_in[(size_t)s0*4+h], y1 = as_in[(size_t)s1*4+h];
        float y2 = as_in[(size_t)s2*4+h], y3 = as_in[(size_t)s3*4+h];
        uint p0 = *(const uint*)(xs + (size_t)s0*128 + c0);
        uint p1 = *(const uint*)(xs + (size_t)s1*128 + c0);
        uint p2 = *(const uint*)(xs + (size_t)s2*128 + c0);
        uint p3 = *(const uint*)(xs + (size_t)s3*128 + c0);
        float al0 = y0 + adh + m0*e0.x + m1*e0.y + m2*e0.z + m3*e0.w;
        float al1 = y1 + adh + m0*e1.x + m1*e1.y + m2*e1.z + m3*e1.w;
        float al2 = y2 + adh + m0*e2.x + m1*e2.y + m2*e2.z + m3*e2.w;
        float al3 = y3 + adh + m0*e3.x + m1*e3.y + m2*e3.z + m3*e3.w;
        al0 = al0 > 0.f ? al0 : 0.2f*al0;
        al1 = al1 > 0.f ? al1 : 0.2f*al1;
        al2 = al2 > 0.f ? al2 : 0.2f*al2;
        al3 = al3 > 0.f ? al3 : 0.2f*al3;
        float w0 = __expf(al0), w1 = __expf(al1), w2 = __expf(al2), w3 = __expf(al3);
        a0 = fmaf(bf2f(p0 & 0xffffu), w0, a0); a1 = fmaf(bf2f(p0 >> 16), w0, a1);
        a0 = fmaf(bf2f(p1 & 0xffffu), w1, a0); a1 = fmaf(bf2f(p1 >> 16), w1, a1);
        a0 = fmaf(bf2f(p2 & 0xffffu), w2, a0); a1 = fmaf(bf2f(p2 >> 16), w2, a1);
        a0 = fmaf(bf2f(p3 & 0xffffu), w3, a0); a1 = fmaf(bf2f(p3 >> 16), w3, a1);
        den += (w0 + w1) + (w2 + w3);
    }
    for (; i < i1; ++i) {
        int s0 = csrs[i];
        float4 e0 = e4c[i];
        float y0 = as_in[(size_t)s0*4+h];
        uint p0 = *(const uint*)(xs + (size_t)s0*128 + c0);
        float al0 = y0 + adh + m0*e0.x + m1*e0.y + m2*e0.z + m3*e0.w;
        al0 = al0 > 0.f ? al0 : 0.2f*al0;
        float w0 = __expf(al0);
        a0 = fmaf(bf2f(p0 & 0xffffu), w0, a0);
        a1 = fmaf(bf2f(p0 >> 16), w0, a1);
        den += w0;
    }
    float inv = 1.f / (den + 1e-16f);
    float v0 = a0 * inv + bias[c0];
    float v1 = a1 * inv + bias[c0 + 1];
    v0 = v0 > 0.f ? v0 : (__expf(v0) - 1.f);
    v1 = v1 > 0.f ? v1 : (__expf(v1) - 1.f);
    uint rp = *(const uint*)(residb + (size_t)n * 384 + c0);
    float r0 = v0 + bf2f(rp & 0xffffu);
    float r1 = v1 + bf2f(rp >> 16);
    float ssum = r0 + r1, ssq = r0 * r0 + r1 * r1;
    #pragma unroll
    for (int o = 1; o < 64; o <<= 1) {
        ssum += __shfl_xor(ssum, o, 64);
        ssq  += __shfl_xor(ssq, o, 64);
    }
    float mu = ssum * (1.f / 128.f);
    float var = ssq * (1.f / 128.f) - mu * mu;
    float rs = rsqrtf(var + 1e-5f);
    float o0 = (r0 - mu) * rs * g[c0] + bln[c0];
    float o1 = (r1 - mu) * rs * g[c0 + 1] + bln[c0 + 1];
    uint pk = (uint)f2bf(o0) | ((uint)f2bf(o1) << 16);
    *(uint*)(outb + (size_t)n * 384 + c0) = pk;
}

// ---------------- fused jk+classifier: out = log_softmax(hcat @ CW^T + cbp)
__global__ __launch_bounds__(256) void k_cls(const ushort* __restrict__ hcatb,
                                             const float* __restrict__ CW,
                                             const float* __restrict__ cbp,
                                             float* __restrict__ out)
{
    __shared__ float sCW[1920], scb[5];
    int t = threadIdx.x;
    for (int i = t; i < 1920; i += 256) sCW[i] = CW[i];
    if (t < 5) scb[t] = cbp[t];
    __syncthreads();
    int n = blockIdx.x * 256 + t;
    if (n >= NN) return;
    float acc[5] = {scb[0], scb[1], scb[2], scb[3], scb[4]};
    const uint2* hr = (const uint2*)(hcatb + (size_t)n * 384);
    #pragma unroll 4
    for (int q = 0; q < 96; ++q) {
        uint2 p = hr[q];
        float v0 = bf2f(p.x & 0xffffu), v1 = bf2f(p.x >> 16);
        float v2 = bf2f(p.y & 0xffffu), v3 = bf2f(p.y >> 16);
        #pragma unroll
        for (int o = 0; o < 5; ++o) {
            const float* w = sCW + o * 384 + q * 4;
            acc[o] += v0*w[0] + v1*w[1] + v2*w[2] + v3*w[3];
        }
    }
    float m = acc[0];
    #pragma unroll
    for (int o = 1; o < 5; ++o) m = fmaxf(m, acc[o]);
    float sum = 0.f;
    #pragma unroll
    for (int o = 0; o < 5; ++o) sum += __expf(acc[o] - m);
    float lse = __logf(sum) + m;
    float* op = out + (size_t)n * 5;
    #pragma unroll
    for (int o = 0; o < 5; ++o) op[o] = acc[o] - lse;
}

extern "C" void kernel_launch(void* const* d_in, const int* in_sizes, int n_in,
                              void* d_out, int out_size, void* d_ws, size_t ws_size,
                              hipStream_t stream)
{
    (void)in_sizes; (void)n_in; (void)out_size; (void)ws_size;
    const float* x        = (const float*)d_in[0];
    const int*   ei       = (const int*)d_in[1];
    const float* eattr    = (const float*)d_in[2];
    const float* ee_w1    = (const float*)d_in[3];
    const float* ee_b1    = (const float*)d_in[4];
    const float* ee_w2    = (const float*)d_in[5];
    const float* ee_b2    = (const float*)d_in[6];
    const float* proj_w   = (const float*)d_in[7];
    const float* proj_b   = (const float*)d_in[8];
    const float* c1_lin   = (const float*)d_in[9];
    const float* c1_asrc  = (const float*)d_in[10];
    const float* c1_adst  = (const float*)d_in[11];
    const float* c1_ledge = (const float*)d_in[12];
    const float* c1_aedge = (const float*)d_in[13];
    const float* c1_bias  = (const float*)d_in[14];
    const float* c2_lin   = (const float*)d_in[15];
    const float* c2_asrc  = (const float*)d_in[16];
    const float* c2_adst  = (const float*)d_in[17];
    const float* c2_ledge = (const float*)d_in[18];
    const float* c2_aedge = (const float*)d_in[19];
    const float* c2_bias  = (const float*)d_in[20];
    const float* n1_g     = (const float*)d_in[21];
    const float* n1_b     = (const float*)d_in[22];
    const float* n2_g     = (const float*)d_in[23];
    const float* n2_b     = (const float*)d_in[24];
    const float* jk_w     = (const float*)d_in[25];
    const float* jk_b     = (const float*)d_in[26];
    const float* cls_w    = (const float*)d_in[27];
    const float* cls_b    = (const float*)d_in[28];
    float* out = (float*)d_out;
    float* ws  = (float*)d_ws;

    // ---- workspace layout (float-element offsets, all 16B-aligned)
    const size_t oM   = 0;                           // 64 (M: 32)
    const size_t oCW  = 64;                          // 1920
    const size_t oCB  = oCW + 1920;                  // 5 -> pad to 2048 total
    const size_t oE4C = 2048;                        // NE float4 = NE*4 f
    const size_t oHB  = oE4C + (size_t)NE * 4;       // hcatb bf16 NN*384 us = NN*192 f
    const size_t oXS  = oHB + (size_t)NN * 192;      // xs bf16 NN*128 us = NN*64 f
    const size_t oXP  = oXS + (size_t)NN * 64;       // xpad bf16 NN*32 us = NN*16 f
    const size_t oWB  = oXP + (size_t)NN * 16;       // pwb 4096us + c1b 4096us + c2b 16384us = 12288 f
    const size_t oAS  = oWB + 12288;                 // NN*4 f
    const size_t oAD  = oAS + (size_t)NN * 4;        // NN*4 f
    const size_t oI   = oAD + (size_t)NN * 4;        // int region

    float*  Mmat  = ws + oM;
    float*  CW    = ws + oCW;
    float*  cbp   = ws + oCB;
    float4* e4c   = (float4*)(ws + oE4C);
    ushort* hcatb = (ushort*)(ws + oHB);
    ushort* xs    = (ushort*)(ws + oXS);
    ushort* xpad  = (ushort*)(ws + oXP);
    ushort* wb    = (ushort*)(ws + oWB);
    ushort* pwb   = wb;                              // 128x32
    ushort* c1b   = wb + 4096;                       // 128x32
    ushort* c2b   = wb + 8192;                       // 128x128
    float*  as_b  = ws + oAS;
    float*  ad_b  = ws + oAD;
    int*    ip    = (int*)(ws + oI);
    int*    deg   = ip;                              // NN
    int*    loc   = ip + NN;                         // NN
    int*    off   = ip + 2 * NN;                     // NN+16
    int*    cur   = ip + 3 * NN + 16;                // NN
    int*    bsum  = ip + 4 * NN + 16;                // 256
    int*    bcar  = ip + 4 * NN + 272;               // 256
    int*    csrs  = ip + 4 * NN + 528;               // NE

    const int EB  = (NE + 255) / 256;          // 3125
    const int NB  = (NN + 255) / 256;          // 196
    const int GB  = (NN + 127) / 128;          // 391
    const int WB2 = (NN + 3) / 4;              // 12500

    // ---- CSR offsets
    k_zero_int<<<NB, 256, 0, stream>>>(deg, NN);
    k_hist<<<EB, 256, 0, stream>>>(ei, deg);
    k_scan_blk<<<NB, 256, 0, stream>>>(deg, loc, bsum);
    k_scan_top<<<1, 256, 0, stream>>>(bsum, bcar, off + NN, NB);
    k_scan_add<<<NB, 256, 0, stream>>>(loc, bcar, off, cur);

    // ---- tiny precomputes (M, CW, cbp) + fused edge-MLP+scatter
    k_prep2<<<8, 256, 0, stream>>>(c1_ledge, c1_aedge, c2_ledge, c2_aedge,
                                   jk_w, jk_b, cls_w, cls_b, Mmat, CW, cbp);
    k_edge_scatter<<<EB, 256, 0, stream>>>(eattr, ee_w1, ee_b1, ee_w2, ee_b2,
                                           ei, cur, csrs, e4c);

    // ---- weight/input conversion to bf16
    k_cvt_pad<<<(NN*32 + 255)/256, 256, 0, stream>>>(x, xpad, NN, 16, 32);
    k_cvt_pad<<<16, 256, 0, stream>>>(proj_w, pwb, 128, 16, 32);
    k_cvt_pad<<<16, 256, 0, stream>>>(c1_lin, c1b, 128, 16, 32);
    k_cvt_pad<<<64, 256, 0, stream>>>(c2_lin, c2b, 128, 128, 128);

    // ---- h0 (bf16, hcat col 0) ; xs1
    gemm_bf16<<<GB, 256, 0, stream>>>(xpad, 32, 32, pwb, 32, proj_b, hcatb, 384, NN);
    gemm_bf16<<<GB, 256, 0, stream>>>(xpad, 32, 32, c1b, 32, nullptr, xs, 128, NN);

    // ---- conv1
    k_att_reduce<<<NB, 256, 0, stream>>>(xs, c1_asrc, c1_adst, as_b, ad_b);
    k_agg2<<<WB2, 256, 0, stream>>>(off, csrs, e4c, as_b, ad_b, Mmat,
                                    xs, c1_bias, hcatb, n1_g, n1_b, hcatb + 128);

    // ---- conv2
    gemm_bf16<<<GB, 256, 0, stream>>>(hcatb + 128, 384, 128, c2b, 128, nullptr, xs, 128, NN);
    k_att_reduce<<<NB, 256, 0, stream>>>(xs, c2_asrc, c2_adst, as_b, ad_b);
    k_agg2<<<WB2, 256, 0, stream>>>(off, csrs, e4c, as_b, ad_b, Mmat + 16,
                                    xs, c2_bias, hcatb + 128, n2_g, n2_b, hcatb + 256);

    // ---- fused jk+classifier+log_softmax
    k_cls<<<NB, 256, 0, stream>>>(hcatb, CW, cbp, out);
}

// Round 5
// 418.898 us; speedup vs baseline: 8.0432x; 1.0205x over previous
//
#include <hip/hip_runtime.h>
#include <cstdint>

#define NN 50000
#define NE 800000

using short8  = __attribute__((ext_vector_type(8))) short;
using float4v = __attribute__((ext_vector_type(4))) float;

__device__ __forceinline__ ushort f2bf(float f) {
    uint u = __float_as_uint(f);
    uint r = (u + 0x7fffu + ((u >> 16) & 1u)) >> 16;
    return (ushort)r;
}
__device__ __forceinline__ float bf2f(uint u) {
    return __uint_as_float(u << 16);
}

// ---------------- fused tiny precompute + weight cvt:
//  [0,32)      M[h][k] for both convs
//  [32,1952)   CW[5,384] = cls_w @ jk_w
//  [1952,1957) cbp[5] = cls_w @ jk_b + cls_b
//  [2048,10240)  w01b bf16 [256,32]: rows 0-127 proj_w (K 16->32 pad), rows 128-255 c1_lin
//  [10240,26624) c2b bf16 [128,128]
__global__ __launch_bounds__(256) void k_prep2(const float* __restrict__ le1, const float* __restrict__ ae1,
                                               const float* __restrict__ le2, const float* __restrict__ ae2,
                                               const float* __restrict__ jkw, const float* __restrict__ jkb,
                                               const float* __restrict__ clw, const float* __restrict__ clb,
                                               const float* __restrict__ projw, const float* __restrict__ c1lin,
                                               const float* __restrict__ c2lin,
                                               float* __restrict__ M, float* __restrict__ CW,
                                               float* __restrict__ cbp,
                                               ushort* __restrict__ w01b, ushort* __restrict__ c2b)
{
    int idx = blockIdx.x * 256 + threadIdx.x;
    if (idx < 32) {
        const float* le = (idx < 16) ? le1 : le2;
        const float* ae = (idx < 16) ? ae1 : ae2;
        int hk = idx & 15, h = hk >> 2, k = hk & 3;
        float s = 0.f;
        for (int c = 0; c < 32; ++c)
            s += le[(h * 32 + c) * 4 + k] * ae[h * 32 + c];
        M[idx] = s;
    } else if (idx < 1952) {
        int o = idx - 32;
        int r = o / 384, c = o - r * 384;
        float s = 0.f;
        for (int k = 0; k < 128; ++k)
            s += clw[r * 128 + k] * jkw[(size_t)k * 384 + c];
        CW[o] = s;
    } else if (idx < 1957) {
        int r = idx - 1952;
        float s = clb[r];
        for (int k = 0; k < 128; ++k)
            s += clw[r * 128 + k] * jkb[k];
        cbp[r] = s;
    } else if (idx >= 2048 && idx < 10240) {
        int o = idx - 2048;
        int r = o >> 5, c = o & 31;
        float v = 0.f;
        if (c < 16) v = (r < 128) ? projw[r * 16 + c] : c1lin[(r - 128) * 16 + c];
        w01b[o] = f2bf(v);
    } else if (idx >= 10240 && idx < 26624) {
        int o = idx - 10240;
        c2b[o] = f2bf(c2lin[o]);
    }
}

// ---------------- CSR build ----------------
__global__ void k_zero_int(int* __restrict__ p, int cnt)
{
    int i = blockIdx.x * 256 + threadIdx.x;
    if (i < cnt) p[i] = 0;
}

// ---------------- fused edge encoder MLP (contiguous e4 write) + dst histogram
__global__ __launch_bounds__(256) void k_edge_mlp(const float* __restrict__ ea,
                                                  const float* __restrict__ w1,
                                                  const float* __restrict__ b1,
                                                  const float* __restrict__ w2,
                                                  const float* __restrict__ b2,
                                                  const int* __restrict__ ei,
                                                  int* __restrict__ deg,
                                                  float4* __restrict__ e4out)
{
    __shared__ float sw1[256], sb1[32], sw2[128], sb2[4];
    int t = threadIdx.x;
    sw1[t] = w1[t];
    if (t < 128) sw2[t] = w2[t];
    if (t < 32)  sb1[t] = b1[t];
    if (t < 4)   sb2[t] = b2[t];
    __syncthreads();
    int e = blockIdx.x * 256 + t;
    if (e >= NE) return;
    float4 x0 = *(const float4*)(ea + (size_t)e * 8);
    float4 x1 = *(const float4*)(ea + (size_t)e * 8 + 4);
    float o0 = sb2[0], o1 = sb2[1], o2 = sb2[2], o3 = sb2[3];
    #pragma unroll
    for (int j = 0; j < 32; ++j) {
        const float* w = sw1 + j * 8;
        float s = sb1[j] + w[0]*x0.x + w[1]*x0.y + w[2]*x0.z + w[3]*x0.w
                         + w[4]*x1.x + w[5]*x1.y + w[6]*x1.z + w[7]*x1.w;
        s = fmaxf(s, 0.f);
        o0 += sw2[0*32+j] * s; o1 += sw2[1*32+j] * s;
        o2 += sw2[2*32+j] * s; o3 += sw2[3*32+j] * s;
    }
    e4out[e] = make_float4(o0, o1, o2, o3);
    atomicAdd(&deg[ei[NE + e]], 1);
}

__global__ __launch_bounds__(256) void k_scan_blk(const int* __restrict__ deg,
                                                  int* __restrict__ loc,
                                                  int* __restrict__ bsum)
{
    __shared__ int tmp[256];
    int t = threadIdx.x;
    int i = blockIdx.x * 256 + t;
    int v = (i < NN) ? deg[i] : 0;
    tmp[t] = v;
    __syncthreads();
    #pragma unroll
    for (int o = 1; o < 256; o <<= 1) {
        int add = (t >= o) ? tmp[t - o] : 0;
        __syncthreads();
        tmp[t] += add;
        __syncthreads();
    }
    if (i < NN) loc[i] = tmp[t] - v;
    if (t == 255) bsum[blockIdx.x] = tmp[255];
}

__global__ __launch_bounds__(256) void k_scan_top(const int* __restrict__ bsum,
                                                  int* __restrict__ bcarry,
                                                  int* __restrict__ total_out, int nb)
{
    __shared__ int tmp[256];
    int t = threadIdx.x;
    int v = (t < nb) ? bsum[t] : 0;
    tmp[t] = v;
    __syncthreads();
    #pragma unroll
    for (int o = 1; o < 256; o <<= 1) {
        int add = (t >= o) ? tmp[t - o] : 0;
        __syncthreads();
        tmp[t] += add;
        __syncthreads();
    }
    if (t < nb) bcarry[t] = tmp[t] - v;
    if (t == 255) *total_out = tmp[255];
}

__global__ __launch_bounds__(256) void k_scan_add(const int* __restrict__ loc,
                                                  const int* __restrict__ bcarry,
                                                  int* __restrict__ off,
                                                  int* __restrict__ cur)
{
    int i = blockIdx.x * 256 + threadIdx.x;
    if (i < NN) {
        int o = loc[i] + bcarry[blockIdx.x];
        off[i] = o;
        cur[i] = o;
    }
}

// ---------------- scatter only (src, e): 8 B payload, 6.4 MB buffer (L2-friendly)
__global__ __launch_bounds__(256) void k_scatter2(const int* __restrict__ ei,
                                                  int* __restrict__ cursor,
                                                  int2* __restrict__ csr2)
{
    int e = blockIdx.x * 256 + threadIdx.x;
    if (e >= NE) return;
    int src = ei[e], dst = ei[NE + e];
    int p = atomicAdd(&cursor[dst], 1);
    csr2[p] = make_int2(src, e);
}

// ---------------- fused GEMM pair from x (fp32, K=16 padded to 32 inline):
//  h0 = x@proj_w^T + proj_b -> hcatb[:,0:128] ; xs1 = x@c1_lin^T -> xs
//  w01b stacked [256,32] bf16 (rows 0-127 proj, 128-255 c1)
__global__ __launch_bounds__(256) void k_gemm1(const float* __restrict__ x,
                                               const ushort* __restrict__ w01,
                                               const float* __restrict__ pbias,
                                               ushort* __restrict__ hcatb,
                                               ushort* __restrict__ xs, int M)
{
    int t = threadIdx.x;
    int wv = t >> 6, lane = t & 63;
    int quad = lane >> 4, r16 = lane & 15;
    int m0 = blockIdx.x * 128 + wv * 32;
    int ar0 = m0 + r16;      if (ar0 >= M) ar0 = M - 1;
    int ar1 = m0 + 16 + r16; if (ar1 >= M) ar1 = M - 1;
    short8 a0 = (short8){0,0,0,0,0,0,0,0}, a1 = a0;
    if (quad < 2) {
        const float* p0 = x + (size_t)ar0 * 16 + quad * 8;
        const float* p1 = x + (size_t)ar1 * 16 + quad * 8;
        float4 u0 = *(const float4*)p0, u1 = *(const float4*)(p0 + 4);
        float4 v0 = *(const float4*)p1, v1 = *(const float4*)(p1 + 4);
        a0[0]=(short)f2bf(u0.x); a0[1]=(short)f2bf(u0.y); a0[2]=(short)f2bf(u0.z); a0[3]=(short)f2bf(u0.w);
        a0[4]=(short)f2bf(u1.x); a0[5]=(short)f2bf(u1.y); a0[6]=(short)f2bf(u1.z); a0[7]=(short)f2bf(u1.w);
        a1[0]=(short)f2bf(v0.x); a1[1]=(short)f2bf(v0.y); a1[2]=(short)f2bf(v0.z); a1[3]=(short)f2bf(v0.w);
        a1[4]=(short)f2bf(v1.x); a1[5]=(short)f2bf(v1.y); a1[6]=(short)f2bf(v1.z); a1[7]=(short)f2bf(v1.w);
    }
    float4v acc[2][16];
    #pragma unroll
    for (int i = 0; i < 2; ++i)
        #pragma unroll
        for (int j = 0; j < 16; ++j) acc[i][j] = (float4v){0.f, 0.f, 0.f, 0.f};
    #pragma unroll
    for (int nt = 0; nt < 16; ++nt) {
        short8 b = *(const short8*)(w01 + (size_t)(nt * 16 + r16) * 32 + quad * 8);
        acc[0][nt] = __builtin_amdgcn_mfma_f32_16x16x32_bf16(a0, b, acc[0][nt], 0, 0, 0);
        acc[1][nt] = __builtin_amdgcn_mfma_f32_16x16x32_bf16(a1, b, acc[1][nt], 0, 0, 0);
    }
    #pragma unroll
    for (int rt = 0; rt < 2; ++rt) {
        #pragma unroll
        for (int nt = 0; nt < 16; ++nt) {
            int col = (nt & 7) * 16 + r16;
            float bv = (nt < 8) ? pbias[col] : 0.f;
            #pragma unroll
            for (int r = 0; r < 4; ++r) {
                int row = m0 + rt * 16 + quad * 4 + r;
                if (row < M) {
                    float v = acc[rt][nt][r] + bv;
                    if (nt < 8) hcatb[(size_t)row * 384 + col] = f2bf(v);
                    else        xs[(size_t)row * 128 + col] = f2bf(v);
                }
            }
        }
    }
}

// ---------------- bf16 MFMA GEMM: Cb[M,128] = A[M,K]*W[128,K]^T, bf16 out
__global__ __launch_bounds__(256) void gemm_bf16(const ushort* __restrict__ A, int lda, int K,
                                                 const ushort* __restrict__ W, int ldw,
                                                 ushort* __restrict__ Cb, int ldcb, int M)
{
    int t = threadIdx.x;
    int wv = t >> 6, lane = t & 63;
    int quad = lane >> 4, r16 = lane & 15;
    int m0 = blockIdx.x * 128 + wv * 32;
    float4v acc[2][8];
    #pragma unroll
    for (int i = 0; i < 2; ++i)
        #pragma unroll
        for (int j = 0; j < 8; ++j) acc[i][j] = (float4v){0.f, 0.f, 0.f, 0.f};
    int ar0 = m0 + r16;      if (ar0 >= M) ar0 = M - 1;
    int ar1 = m0 + 16 + r16; if (ar1 >= M) ar1 = M - 1;
    const ushort* a0p = A + (size_t)ar0 * lda + quad * 8;
    const ushort* a1p = A + (size_t)ar1 * lda + quad * 8;
    const ushort* wp  = W + (size_t)r16 * ldw + quad * 8;
    for (int k0 = 0; k0 < K; k0 += 32) {
        short8 a0 = *(const short8*)(a0p + k0);
        short8 a1 = *(const short8*)(a1p + k0);
        #pragma unroll
        for (int nt = 0; nt < 8; ++nt) {
            short8 b = *(const short8*)(wp + (size_t)(nt * 16) * ldw + k0);
            acc[0][nt] = __builtin_amdgcn_mfma_f32_16x16x32_bf16(a0, b, acc[0][nt], 0, 0, 0);
            acc[1][nt] = __builtin_amdgcn_mfma_f32_16x16x32_bf16(a1, b, acc[1][nt], 0, 0, 0);
        }
    }
    #pragma unroll
    for (int rt = 0; rt < 2; ++rt) {
        #pragma unroll
        for (int nt = 0; nt < 8; ++nt) {
            int col = nt * 16 + r16;
            #pragma unroll
            for (int r = 0; r < 4; ++r) {
                int row = m0 + rt * 16 + quad * 4 + r;
                if (row < M)
                    Cb[(size_t)row * ldcb + col] = f2bf(acc[rt][nt][r]);
            }
        }
    }
}

// ---------------- per-node attention coefficients from bf16 xs
__global__ __launch_bounds__(256) void k_att_reduce(const ushort* __restrict__ xs,
                                                    const float* __restrict__ att_src,
                                                    const float* __restrict__ att_dst,
                                                    float* __restrict__ as_out,
                                                    float* __restrict__ ad_out)
{
    __shared__ float ssrc[128], sdst[128];
    int t = threadIdx.x;
    if (t < 128) { ssrc[t] = att_src[t]; sdst[t] = att_dst[t]; }
    __syncthreads();
    int n = blockIdx.x * 256 + t;
    if (n >= NN) return;
    float s[4] = {0,0,0,0}, d[4] = {0,0,0,0};
    const uint2* xr = (const uint2*)(xs + (size_t)n * 128);
    #pragma unroll
    for (int q = 0; q < 32; ++q) {
        uint2 p = xr[q];
        float v0 = bf2f(p.x & 0xffffu), v1 = bf2f(p.x >> 16);
        float v2 = bf2f(p.y & 0xffffu), v3 = bf2f(p.y >> 16);
        int h = q >> 3;
        const float* aw = ssrc + q * 4;
        const float* dw = sdst + q * 4;
        s[h] += v0*aw[0] + v1*aw[1] + v2*aw[2] + v3*aw[3];
        d[h] += v0*dw[0] + v1*dw[1] + v2*dw[2] + v3*dw[3];
    }
    *(float4*)(as_out + (size_t)n * 4) = make_float4(s[0], s[1], s[2], s[3]);
    *(float4*)(ad_out + (size_t)n * 4) = make_float4(d[0], d[1], d[2], d[3]);
}

// ---------------- fused: CSR gather + inline alpha + aggregate + normalize
//                  + bias + ELU + residual(bf16) + LayerNorm -> bf16
// wave per node; csr2 contiguous (src,e); e4 gathered by e (wave-uniform)
__global__ __launch_bounds__(256) void k_agg2(const int* __restrict__ off,
                                              const int2* __restrict__ csr2,
                                              const float4* __restrict__ e4g,
                                              const float* __restrict__ as_in,
                                              const float* __restrict__ ad_in,
                                              const float* __restrict__ Mm,
                                              const ushort* __restrict__ xs,
                                              const float* __restrict__ bias,
                                              const ushort* __restrict__ residb,
                                              const float* __restrict__ g,
                                              const float* __restrict__ bln,
                                              ushort* __restrict__ outb)
{
    int wave = threadIdx.x >> 6;
    int lane = threadIdx.x & 63;
    int n = blockIdx.x * 4 + wave;
    if (n >= NN) return;
    int i0 = off[n], i1 = off[n + 1];
    int c0 = lane * 2;
    int h = lane >> 4;
    float m0 = Mm[h*4+0], m1 = Mm[h*4+1], m2 = Mm[h*4+2], m3 = Mm[h*4+3];
    float adh = ad_in[(size_t)n * 4 + h];
    float a0 = 0.f, a1 = 0.f, den = 0.f;
    int i = i0;
    for (; i + 4 <= i1; i += 4) {
        int2 se0 = csr2[i], se1 = csr2[i+1], se2 = csr2[i+2], se3 = csr2[i+3];
        float4 e0 = e4g[se0.y], e1 = e4g[se1.y], e2 = e4g[se2.y], e3 = e4g[se3.y];
        float y0 = as_in[(size_t)se0.x*4+h], y1 = as_in[(size_t)se1.x*4+h];
        float y2 = as_in[(size_t)se2.x*4+h], y3 = as_in[(size_t)se3.x*4+h];
        uint p0 = *(const uint*)(xs + (size_t)se0.x*128 + c0);
        uint p1 = *(const uint*)(xs + (size_t)se1.x*128 + c0);
        uint p2 = *(const uint*)(xs + (size_t)se2.x*128 + c0);
        uint p3 = *(const uint*)(xs + (size_t)se3.x*128 + c0);
        float al0 = y0 + adh + m0*e0.x + m1*e0.y + m2*e0.z + m3*e0.w;
        float al1 = y1 + adh + m0*e1.x + m1*e1.y + m2*e1.z + m3*e1.w;
        float al2 = y2 + adh + m0*e2.x + m1*e2.y + m2*e2.z + m3*e2.w;
        float al3 = y3 + adh + m0*e3.x + m1*e3.y + m2*e3.z + m3*e3.w;
        al0 = al0 > 0.f ? al0 : 0.2f*al0;
        al1 = al1 > 0.f ? al1 : 0.2f*al1;
        al2 = al2 > 0.f ? al2 : 0.2f*al2;
        al3 = al3 > 0.f ? al3 : 0.2f*al3;
        float w0 = __expf(al0), w1 = __expf(al1), w2 = __expf(al2), w3 = __expf(al3);
        a0 = fmaf(bf2f(p0 & 0xffffu), w0, a0); a1 = fmaf(bf2f(p0 >> 16), w0, a1);
        a0 = fmaf(bf2f(p1 & 0xffffu), w1, a0); a1 = fmaf(bf2f(p1 >> 16), w1, a1);
        a0 = fmaf(bf2f(p2 & 0xffffu), w2, a0); a1 = fmaf(bf2f(p2 >> 16), w2, a1);
        a0 = fmaf(bf2f(p3 & 0xffffu), w3, a0); a1 = fmaf(bf2f(p3 >> 16), w3, a1);
        den += (w0 + w1) + (w2 + w3);
    }
    for (; i < i1; ++i) {
        int2 se0 = csr2[i];
        float4 e0 = e4g[se0.y];
        float y0 = as_in[(size_t)se0.x*4+h];
        uint p0 = *(const uint*)(xs + (size_t)se0.x*128 + c0);
        float al0 = y0 + adh + m0*e0.x + m1*e0.y + m2*e0.z + m3*e0.w;
        al0 = al0 > 0.f ? al0 : 0.2f*al0;
        float w0 = __expf(al0);
        a0 = fmaf(bf2f(p0 & 0xffffu), w0, a0);
        a1 = fmaf(bf2f(p0 >> 16), w0, a1);
        den += w0;
    }
    float inv = 1.f / (den + 1e-16f);
    float v0 = a0 * inv + bias[c0];
    float v1 = a1 * inv + bias[c0 + 1];
    v0 = v0 > 0.f ? v0 : (__expf(v0) - 1.f);
    v1 = v1 > 0.f ? v1 : (__expf(v1) - 1.f);
    uint rp = *(const uint*)(residb + (size_t)n * 384 + c0);
    float r0 = v0 + bf2f(rp & 0xffffu);
    float r1 = v1 + bf2f(rp >> 16);
    float ssum = r0 + r1, ssq = r0 * r0 + r1 * r1;
    #pragma unroll
    for (int o = 1; o < 64; o <<= 1) {
        ssum += __shfl_xor(ssum, o, 64);
        ssq  += __shfl_xor(ssq, o, 64);
    }
    float mu = ssum * (1.f / 128.f);
    float var = ssq * (1.f / 128.f) - mu * mu;
    float rs = rsqrtf(var + 1e-5f);
    float o0 = (r0 - mu) * rs * g[c0] + bln[c0];
    float o1 = (r1 - mu) * rs * g[c0 + 1] + bln[c0 + 1];
    uint pk = (uint)f2bf(o0) | ((uint)f2bf(o1) << 16);
    *(uint*)(outb + (size_t)n * 384 + c0) = pk;
}

// ---------------- fused jk+classifier: out = log_softmax(hcat @ CW^T + cbp)
__global__ __launch_bounds__(256) void k_cls(const ushort* __restrict__ hcatb,
                                             const float* __restrict__ CW,
                                             const float* __restrict__ cbp,
                                             float* __restrict__ out)
{
    __shared__ float sCW[1920], scb[5];
    int t = threadIdx.x;
    for (int i = t; i < 1920; i += 256) sCW[i] = CW[i];
    if (t < 5) scb[t] = cbp[t];
    __syncthreads();
    int n = blockIdx.x * 256 + t;
    if (n >= NN) return;
    float acc[5] = {scb[0], scb[1], scb[2], scb[3], scb[4]};
    const uint2* hr = (const uint2*)(hcatb + (size_t)n * 384);
    #pragma unroll 4
    for (int q = 0; q < 96; ++q) {
        uint2 p = hr[q];
        float v0 = bf2f(p.x & 0xffffu), v1 = bf2f(p.x >> 16);
        float v2 = bf2f(p.y & 0xffffu), v3 = bf2f(p.y >> 16);
        #pragma unroll
        for (int o = 0; o < 5; ++o) {
            const float* w = sCW + o * 384 + q * 4;
            acc[o] += v0*w[0] + v1*w[1] + v2*w[2] + v3*w[3];
        }
    }
    float m = acc[0];
    #pragma unroll
    for (int o = 1; o < 5; ++o) m = fmaxf(m, acc[o]);
    float sum = 0.f;
    #pragma unroll
    for (int o = 0; o < 5; ++o) sum += __expf(acc[o] - m);
    float lse = __logf(sum) + m;
    float* op = out + (size_t)n * 5;
    #pragma unroll
    for (int o = 0; o < 5; ++o) op[o] = acc[o] - lse;
}

extern "C" void kernel_launch(void* const* d_in, const int* in_sizes, int n_in,
                              void* d_out, int out_size, void* d_ws, size_t ws_size,
                              hipStream_t stream)
{
    (void)in_sizes; (void)n_in; (void)out_size; (void)ws_size;
    const float* x        = (const float*)d_in[0];
    const int*   ei       = (const int*)d_in[1];
    const float* eattr    = (const float*)d_in[2];
    const float* ee_w1    = (const float*)d_in[3];
    const float* ee_b1    = (const float*)d_in[4];
    const float* ee_w2    = (const float*)d_in[5];
    const float* ee_b2    = (const float*)d_in[6];
    const float* proj_w   = (const float*)d_in[7];
    const float* proj_b   = (const float*)d_in[8];
    const float* c1_lin   = (const float*)d_in[9];
    const float* c1_asrc  = (const float*)d_in[10];
    const float* c1_adst  = (const float*)d_in[11];
    const float* c1_ledge = (const float*)d_in[12];
    const float* c1_aedge = (const float*)d_in[13];
    const float* c1_bias  = (const float*)d_in[14];
    const float* c2_lin   = (const float*)d_in[15];
    const float* c2_asrc  = (const float*)d_in[16];
    const float* c2_adst  = (const float*)d_in[17];
    const float* c2_ledge = (const float*)d_in[18];
    const float* c2_aedge = (const float*)d_in[19];
    const float* c2_bias  = (const float*)d_in[20];
    const float* n1_g     = (const float*)d_in[21];
    const float* n1_b     = (const float*)d_in[22];
    const float* n2_g     = (const float*)d_in[23];
    const float* n2_b     = (const float*)d_in[24];
    const float* jk_w     = (const float*)d_in[25];
    const float* jk_b     = (const float*)d_in[26];
    const float* cls_w    = (const float*)d_in[27];
    const float* cls_b    = (const float*)d_in[28];
    float* out = (float*)d_out;
    float* ws  = (float*)d_ws;

    // ---- workspace layout (float-element offsets, 16B-aligned)
    const size_t oM   = 0;                           // 32 (+pad)
    const size_t oCW  = 64;                          // 1920
    const size_t oCB  = oCW + 1920;                  // 5 -> region ends at 2048
    const size_t oE4  = 2048;                        // e4 edge-order: NE*4 f
    const size_t oHB  = oE4 + (size_t)NE * 4;        // hcatb bf16 NN*384 us = NN*192 f
    const size_t oXS  = oHB + (size_t)NN * 192;      // xs bf16 NN*128 us = NN*64 f
    const size_t oWB  = oXS + (size_t)NN * 64;       // w01b 8192us + c2b 16384us = 12288 f
    const size_t oAS  = oWB + 12288;                 // NN*4
    const size_t oAD  = oAS + (size_t)NN * 4;        // NN*4
    const size_t oI   = oAD + (size_t)NN * 4;        // int region

    float*  Mmat  = ws + oM;
    float*  CW    = ws + oCW;
    float*  cbp   = ws + oCB;
    float4* e4g   = (float4*)(ws + oE4);
    ushort* hcatb = (ushort*)(ws + oHB);
    ushort* xs    = (ushort*)(ws + oXS);
    ushort* w01b  = (ushort*)(ws + oWB);             // [256,32]
    ushort* c2b   = w01b + 8192;                     // [128,128]
    float*  as_b  = ws + oAS;
    float*  ad_b  = ws + oAD;
    int*    ip    = (int*)(ws + oI);
    int*    deg   = ip;                              // NN
    int*    loc   = ip + NN;                         // NN
    int*    off   = ip + 2 * NN;                     // NN+16
    int*    cur   = ip + 3 * NN + 16;                // NN
    int*    bsum  = ip + 4 * NN + 16;                // 256
    int*    bcar  = ip + 4 * NN + 272;               // 256
    int2*   csr2  = (int2*)(ip + 4 * NN + 528);      // NE int2

    const int EB  = (NE + 255) / 256;          // 3125
    const int NB  = (NN + 255) / 256;          // 196
    const int GB  = (NN + 127) / 128;          // 391
    const int WB2 = (NN + 3) / 4;              // 12500

    // ---- CSR offsets + edge MLP (hist fused)
    k_zero_int<<<NB, 256, 0, stream>>>(deg, NN);
    k_prep2<<<104, 256, 0, stream>>>(c1_ledge, c1_aedge, c2_ledge, c2_aedge,
                                     jk_w, jk_b, cls_w, cls_b,
                                     proj_w, c1_lin, c2_lin,
                                     Mmat, CW, cbp, w01b, c2b);
    k_edge_mlp<<<EB, 256, 0, stream>>>(eattr, ee_w1, ee_b1, ee_w2, ee_b2, ei, deg, e4g);
    k_scan_blk<<<NB, 256, 0, stream>>>(deg, loc, bsum);
    k_scan_top<<<1, 256, 0, stream>>>(bsum, bcar, off + NN, NB);
    k_scan_add<<<NB, 256, 0, stream>>>(loc, bcar, off, cur);
    k_scatter2<<<EB, 256, 0, stream>>>(ei, cur, csr2);

    // ---- h0 + xs1 in one pass from fp32 x
    k_gemm1<<<GB, 256, 0, stream>>>(x, w01b, proj_b, hcatb, xs, NN);

    // ---- conv1
    k_att_reduce<<<NB, 256, 0, stream>>>(xs, c1_asrc, c1_adst, as_b, ad_b);
    k_agg2<<<WB2, 256, 0, stream>>>(off, csr2, e4g, as_b, ad_b, Mmat,
                                    xs, c1_bias, hcatb, n1_g, n1_b, hcatb + 128);

    // ---- conv2
    gemm_bf16<<<GB, 256, 0, stream>>>(hcatb + 128, 384, 128, c2b, 128, xs, 128, NN);
    k_att_reduce<<<NB, 256, 0, stream>>>(xs, c2_asrc, c2_adst, as_b, ad_b);
    k_agg2<<<WB2, 256, 0, stream>>>(off, csr2, e4g, as_b, ad_b, Mmat + 16,
                                    xs, c2_bias, hcatb + 128, n2_g, n2_b, hcatb + 256);

    // ---- fused jk+classifier+log_softmax
    k_cls<<<NB, 256, 0, stream>>>(hcatb, CW, cbp, out);
}

// Round 6
// 397.952 us; speedup vs baseline: 8.4666x; 1.0526x over previous
//
#include <hip/hip_runtime.h>
#include <cstdint>

#define NN 50000
#define NE 800000

using short8  = __attribute__((ext_vector_type(8))) short;
using float4v = __attribute__((ext_vector_type(4))) float;

__device__ __forceinline__ ushort f2bf(float f) {
    uint u = __float_as_uint(f);
    uint r = (u + 0x7fffu + ((u >> 16) & 1u)) >> 16;
    return (ushort)r;
}
__device__ __forceinline__ float bf2f(uint u) {
    return __uint_as_float(u << 16);
}

// ---------------- fused tiny precompute + weight cvt + deg zero:
//  idx<NN        deg[idx]=0
//  [0,32)        M[h][k] both convs
//  [32,1952)     CW[5,384] = cls_w @ jk_w
//  [1952,1957)   cbp[5] = cls_w @ jk_b + cls_b
//  [2048,10240)  w01b bf16 [256,32] (proj_w | c1_lin, K 16->32 pad)
//  [10240,26624) c2b bf16 [128,128]
//  [26624,26752) Vmat: Vs1[4,16], Vd1[4,16]  (as1 = x @ Vs1^T)
__global__ __launch_bounds__(256) void k_prep2(const float* __restrict__ le1, const float* __restrict__ ae1,
                                               const float* __restrict__ le2, const float* __restrict__ ae2,
                                               const float* __restrict__ jkw, const float* __restrict__ jkb,
                                               const float* __restrict__ clw, const float* __restrict__ clb,
                                               const float* __restrict__ projw, const float* __restrict__ c1lin,
                                               const float* __restrict__ c2lin,
                                               const float* __restrict__ asrc1, const float* __restrict__ adst1,
                                               float* __restrict__ M, float* __restrict__ CW,
                                               float* __restrict__ cbp,
                                               ushort* __restrict__ w01b, ushort* __restrict__ c2b,
                                               float* __restrict__ Vmat, int* __restrict__ deg)
{
    int idx = blockIdx.x * 256 + threadIdx.x;
    if (idx < NN) deg[idx] = 0;
    if (idx < 32) {
        const float* le = (idx < 16) ? le1 : le2;
        const float* ae = (idx < 16) ? ae1 : ae2;
        int hk = idx & 15, h = hk >> 2, k = hk & 3;
        float s = 0.f;
        for (int c = 0; c < 32; ++c)
            s += le[(h * 32 + c) * 4 + k] * ae[h * 32 + c];
        M[idx] = s;
    } else if (idx < 1952) {
        int o = idx - 32;
        int r = o / 384, c = o - r * 384;
        float s = 0.f;
        for (int k = 0; k < 128; ++k)
            s += clw[r * 128 + k] * jkw[(size_t)k * 384 + c];
        CW[o] = s;
    } else if (idx < 1957) {
        int r = idx - 1952;
        float s = clb[r];
        for (int k = 0; k < 128; ++k)
            s += clw[r * 128 + k] * jkb[k];
        cbp[r] = s;
    } else if (idx >= 2048 && idx < 10240) {
        int o = idx - 2048;
        int r = o >> 5, c = o & 31;
        float v = 0.f;
        if (c < 16) v = (r < 128) ? projw[r * 16 + c] : c1lin[(r - 128) * 16 + c];
        w01b[o] = f2bf(v);
    } else if (idx >= 10240 && idx < 26624) {
        int o = idx - 10240;
        c2b[o] = f2bf(c2lin[o]);
    } else if (idx >= 26624 && idx < 26752) {
        int o = idx - 26624;
        const float* att = (o < 64) ? asrc1 : adst1;
        int oo = o & 63, h = oo >> 4, k = oo & 15;
        float s = 0.f;
        for (int c = 0; c < 32; ++c)
            s += c1lin[(h * 32 + c) * 16 + k] * att[h * 32 + c];
        Vmat[o] = s;
    }
}

// ---------------- conv1 attention coefficients straight from x: as1 = x@Vs1^T etc.
__global__ __launch_bounds__(256) void k_att1(const float* __restrict__ x,
                                              const float* __restrict__ V,
                                              float* __restrict__ as_o,
                                              float* __restrict__ ad_o)
{
    __shared__ float sV[128];
    int t = threadIdx.x;
    if (t < 128) sV[t] = V[t];
    __syncthreads();
    int n = blockIdx.x * 256 + t;
    if (n >= NN) return;
    const float4* xr = (const float4*)(x + (size_t)n * 16);
    float4 x0 = xr[0], x1 = xr[1], x2 = xr[2], x3 = xr[3];
    float xv[16] = {x0.x,x0.y,x0.z,x0.w, x1.x,x1.y,x1.z,x1.w,
                    x2.x,x2.y,x2.z,x2.w, x3.x,x3.y,x3.z,x3.w};
    float s[4], d[4];
    #pragma unroll
    for (int h = 0; h < 4; ++h) {
        float ss = 0.f, dd = 0.f;
        #pragma unroll
        for (int k = 0; k < 16; ++k) {
            ss += xv[k] * sV[h * 16 + k];
            dd += xv[k] * sV[64 + h * 16 + k];
        }
        s[h] = ss; d[h] = dd;
    }
    *(float4*)(as_o + (size_t)n * 4) = make_float4(s[0], s[1], s[2], s[3]);
    *(float4*)(ad_o + (size_t)n * 4) = make_float4(d[0], d[1], d[2], d[3]);
}

// ---------------- fused edge MLP + conv1 softmax numerator (bf16) + conv2 a_edge + hist
__global__ __launch_bounds__(256) void k_edge_mlp(const float* __restrict__ ea,
                                                  const float* __restrict__ w1,
                                                  const float* __restrict__ b1,
                                                  const float* __restrict__ w2,
                                                  const float* __restrict__ b2,
                                                  const int* __restrict__ ei,
                                                  const float* __restrict__ Mm,
                                                  const float* __restrict__ as1,
                                                  const float* __restrict__ ad1,
                                                  int* __restrict__ deg,
                                                  ushort* __restrict__ exb,
                                                  float4* __restrict__ ae2)
{
    __shared__ float sw1[256], sb1[32], sw2[128], sb2[4], sM[32];
    int t = threadIdx.x;
    sw1[t] = w1[t];
    if (t < 128) sw2[t] = w2[t];
    if (t < 32)  { sb1[t] = b1[t]; sM[t] = Mm[t]; }
    if (t < 4)   sb2[t] = b2[t];
    __syncthreads();
    int e = blockIdx.x * 256 + t;
    if (e >= NE) return;
    int src = ei[e], dst = ei[NE + e];
    float4 s4 = *(const float4*)(as1 + (size_t)src * 4);
    float4 d4 = *(const float4*)(ad1 + (size_t)dst * 4);
    float4 x0 = *(const float4*)(ea + (size_t)e * 8);
    float4 x1 = *(const float4*)(ea + (size_t)e * 8 + 4);
    float o0 = sb2[0], o1 = sb2[1], o2 = sb2[2], o3 = sb2[3];
    #pragma unroll
    for (int j = 0; j < 32; ++j) {
        const float* w = sw1 + j * 8;
        float s = sb1[j] + w[0]*x0.x + w[1]*x0.y + w[2]*x0.z + w[3]*x0.w
                         + w[4]*x1.x + w[5]*x1.y + w[6]*x1.z + w[7]*x1.w;
        s = fmaxf(s, 0.f);
        o0 += sw2[0*32+j] * s; o1 += sw2[1*32+j] * s;
        o2 += sw2[2*32+j] * s; o3 += sw2[3*32+j] * s;
    }
    atomicAdd(&deg[dst], 1);
    float sa[4] = {s4.x, s4.y, s4.z, s4.w};
    float da[4] = {d4.x, d4.y, d4.z, d4.w};
    ushort exq[4];
    float a2[4];
    #pragma unroll
    for (int h = 0; h < 4; ++h) {
        float ae1 = sM[h*4+0]*o0 + sM[h*4+1]*o1 + sM[h*4+2]*o2 + sM[h*4+3]*o3;
        float al = sa[h] + da[h] + ae1;
        al = al > 0.f ? al : 0.2f * al;
        exq[h] = f2bf(__expf(al));
        a2[h] = sM[16+h*4+0]*o0 + sM[16+h*4+1]*o1 + sM[16+h*4+2]*o2 + sM[16+h*4+3]*o3;
    }
    *(uint2*)(exb + (size_t)e * 4) =
        make_uint2((uint)exq[0] | ((uint)exq[1] << 16), (uint)exq[2] | ((uint)exq[3] << 16));
    ae2[e] = make_float4(a2[0], a2[1], a2[2], a2[3]);
}

// ---------------- scan ----------------
__global__ __launch_bounds__(256) void k_scan_blk(const int* __restrict__ deg,
                                                  int* __restrict__ loc,
                                                  int* __restrict__ bsum)
{
    __shared__ int tmp[256];
    int t = threadIdx.x;
    int i = blockIdx.x * 256 + t;
    int v = (i < NN) ? deg[i] : 0;
    tmp[t] = v;
    __syncthreads();
    #pragma unroll
    for (int o = 1; o < 256; o <<= 1) {
        int add = (t >= o) ? tmp[t - o] : 0;
        __syncthreads();
        tmp[t] += add;
        __syncthreads();
    }
    if (i < NN) loc[i] = tmp[t] - v;
    if (t == 255) bsum[blockIdx.x] = tmp[255];
}

__global__ __launch_bounds__(256) void k_scan_top(const int* __restrict__ bsum,
                                                  int* __restrict__ bcarry,
                                                  int* __restrict__ total_out, int nb)
{
    __shared__ int tmp[256];
    int t = threadIdx.x;
    int v = (t < nb) ? bsum[t] : 0;
    tmp[t] = v;
    __syncthreads();
    #pragma unroll
    for (int o = 1; o < 256; o <<= 1) {
        int add = (t >= o) ? tmp[t - o] : 0;
        __syncthreads();
        tmp[t] += add;
        __syncthreads();
    }
    if (t < nb) bcarry[t] = tmp[t] - v;
    if (t == 255) *total_out = tmp[255];
}

__global__ __launch_bounds__(256) void k_scan_add(const int* __restrict__ loc,
                                                  const int* __restrict__ bcarry,
                                                  int* __restrict__ off,
                                                  int* __restrict__ cur)
{
    int i = blockIdx.x * 256 + threadIdx.x;
    if (i < NN) {
        int o = loc[i] + bcarry[blockIdx.x];
        off[i] = o;
        cur[i] = o;
    }
}

__global__ __launch_bounds__(256) void k_scatter2(const int* __restrict__ ei,
                                                  int* __restrict__ cursor,
                                                  int2* __restrict__ csr2)
{
    int e = blockIdx.x * 256 + threadIdx.x;
    if (e >= NE) return;
    int src = ei[e], dst = ei[NE + e];
    int p = atomicAdd(&cursor[dst], 1);
    csr2[p] = make_int2(src, e);
}

// ---------------- fused GEMM pair from x (K=16 pad 32): h0 -> hcatb[:,0:128]; xs1 -> xs
__global__ __launch_bounds__(256) void k_gemm1(const float* __restrict__ x,
                                               const ushort* __restrict__ w01,
                                               const float* __restrict__ pbias,
                                               ushort* __restrict__ hcatb,
                                               ushort* __restrict__ xs, int M)
{
    int t = threadIdx.x;
    int wv = t >> 6, lane = t & 63;
    int quad = lane >> 4, r16 = lane & 15;
    int m0 = blockIdx.x * 128 + wv * 32;
    int ar0 = m0 + r16;      if (ar0 >= M) ar0 = M - 1;
    int ar1 = m0 + 16 + r16; if (ar1 >= M) ar1 = M - 1;
    short8 a0 = (short8){0,0,0,0,0,0,0,0}, a1 = a0;
    if (quad < 2) {
        const float* p0 = x + (size_t)ar0 * 16 + quad * 8;
        const float* p1 = x + (size_t)ar1 * 16 + quad * 8;
        float4 u0 = *(const float4*)p0, u1 = *(const float4*)(p0 + 4);
        float4 v0 = *(const float4*)p1, v1 = *(const float4*)(p1 + 4);
        a0[0]=(short)f2bf(u0.x); a0[1]=(short)f2bf(u0.y); a0[2]=(short)f2bf(u0.z); a0[3]=(short)f2bf(u0.w);
        a0[4]=(short)f2bf(u1.x); a0[5]=(short)f2bf(u1.y); a0[6]=(short)f2bf(u1.z); a0[7]=(short)f2bf(u1.w);
        a1[0]=(short)f2bf(v0.x); a1[1]=(short)f2bf(v0.y); a1[2]=(short)f2bf(v0.z); a1[3]=(short)f2bf(v0.w);
        a1[4]=(short)f2bf(v1.x); a1[5]=(short)f2bf(v1.y); a1[6]=(short)f2bf(v1.z); a1[7]=(short)f2bf(v1.w);
    }
    float4v acc[2][16];
    #pragma unroll
    for (int i = 0; i < 2; ++i)
        #pragma unroll
        for (int j = 0; j < 16; ++j) acc[i][j] = (float4v){0.f, 0.f, 0.f, 0.f};
    #pragma unroll
    for (int nt = 0; nt < 16; ++nt) {
        short8 b = *(const short8*)(w01 + (size_t)(nt * 16 + r16) * 32 + quad * 8);
        acc[0][nt] = __builtin_amdgcn_mfma_f32_16x16x32_bf16(a0, b, acc[0][nt], 0, 0, 0);
        acc[1][nt] = __builtin_amdgcn_mfma_f32_16x16x32_bf16(a1, b, acc[1][nt], 0, 0, 0);
    }
    #pragma unroll
    for (int rt = 0; rt < 2; ++rt) {
        #pragma unroll
        for (int nt = 0; nt < 16; ++nt) {
            int col = (nt & 7) * 16 + r16;
            float bv = (nt < 8) ? pbias[col] : 0.f;
            #pragma unroll
            for (int r = 0; r < 4; ++r) {
                int row = m0 + rt * 16 + quad * 4 + r;
                if (row < M) {
                    float v = acc[rt][nt][r] + bv;
                    if (nt < 8) hcatb[(size_t)row * 384 + col] = f2bf(v);
                    else        xs[(size_t)row * 128 + col] = f2bf(v);
                }
            }
        }
    }
}

// ---------------- bf16 MFMA GEMM: Cb[M,128] = A[M,K]*W[128,K]^T, bf16 out
__global__ __launch_bounds__(256) void gemm_bf16(const ushort* __restrict__ A, int lda, int K,
                                                 const ushort* __restrict__ W, int ldw,
                                                 ushort* __restrict__ Cb, int ldcb, int M)
{
    int t = threadIdx.x;
    int wv = t >> 6, lane = t & 63;
    int quad = lane >> 4, r16 = lane & 15;
    int m0 = blockIdx.x * 128 + wv * 32;
    float4v acc[2][8];
    #pragma unroll
    for (int i = 0; i < 2; ++i)
        #pragma unroll
        for (int j = 0; j < 8; ++j) acc[i][j] = (float4v){0.f, 0.f, 0.f, 0.f};
    int ar0 = m0 + r16;      if (ar0 >= M) ar0 = M - 1;
    int ar1 = m0 + 16 + r16; if (ar1 >= M) ar1 = M - 1;
    const ushort* a0p = A + (size_t)ar0 * lda + quad * 8;
    const ushort* a1p = A + (size_t)ar1 * lda + quad * 8;
    const ushort* wp  = W + (size_t)r16 * ldw + quad * 8;
    for (int k0 = 0; k0 < K; k0 += 32) {
        short8 a0 = *(const short8*)(a0p + k0);
        short8 a1 = *(const short8*)(a1p + k0);
        #pragma unroll
        for (int nt = 0; nt < 8; ++nt) {
            short8 b = *(const short8*)(wp + (size_t)(nt * 16) * ldw + k0);
            acc[0][nt] = __builtin_amdgcn_mfma_f32_16x16x32_bf16(a0, b, acc[0][nt], 0, 0, 0);
            acc[1][nt] = __builtin_amdgcn_mfma_f32_16x16x32_bf16(a1, b, acc[1][nt], 0, 0, 0);
        }
    }
    #pragma unroll
    for (int rt = 0; rt < 2; ++rt) {
        #pragma unroll
        for (int nt = 0; nt < 8; ++nt) {
            int col = nt * 16 + r16;
            #pragma unroll
            for (int r = 0; r < 4; ++r) {
                int row = m0 + rt * 16 + quad * 4 + r;
                if (row < M)
                    Cb[(size_t)row * ldcb + col] = f2bf(acc[rt][nt][r]);
            }
        }
    }
}

// ---------------- per-node attention coefficients from bf16 xs (conv2)
__global__ __launch_bounds__(256) void k_att_reduce(const ushort* __restrict__ xs,
                                                    const float* __restrict__ att_src,
                                                    const float* __restrict__ att_dst,
                                                    float* __restrict__ as_out,
                                                    float* __restrict__ ad_out)
{
    __shared__ float ssrc[128], sdst[128];
    int t = threadIdx.x;
    if (t < 128) { ssrc[t] = att_src[t]; sdst[t] = att_dst[t]; }
    __syncthreads();
    int n = blockIdx.x * 256 + t;
    if (n >= NN) return;
    float s[4] = {0,0,0,0}, d[4] = {0,0,0,0};
    const uint2* xr = (const uint2*)(xs + (size_t)n * 128);
    #pragma unroll
    for (int q = 0; q < 32; ++q) {
        uint2 p = xr[q];
        float v0 = bf2f(p.x & 0xffffu), v1 = bf2f(p.x >> 16);
        float v2 = bf2f(p.y & 0xffffu), v3 = bf2f(p.y >> 16);
        int h = q >> 3;
        const float* aw = ssrc + q * 4;
        const float* dw = sdst + q * 4;
        s[h] += v0*aw[0] + v1*aw[1] + v2*aw[2] + v3*aw[3];
        d[h] += v0*dw[0] + v1*dw[1] + v2*dw[2] + v3*dw[3];
    }
    *(float4*)(as_out + (size_t)n * 4) = make_float4(s[0], s[1], s[2], s[3]);
    *(float4*)(ad_out + (size_t)n * 4) = make_float4(d[0], d[1], d[2], d[3]);
}

// ---------------- conv2 softmax numerator: ex = exp(leaky(ae2 + as[src] + ad[dst])) -> bf16
__global__ __launch_bounds__(256) void k_edge_soft2(const int* __restrict__ ei,
                                                    const float* __restrict__ as_in,
                                                    const float* __restrict__ ad_in,
                                                    const float4* __restrict__ ae2,
                                                    ushort* __restrict__ exb)
{
    int e = blockIdx.x * 256 + threadIdx.x;
    if (e >= NE) return;
    int src = ei[e], dst = ei[NE + e];
    float4 s4 = *(const float4*)(as_in + (size_t)src * 4);
    float4 d4 = *(const float4*)(ad_in + (size_t)dst * 4);
    float4 a = ae2[e];
    float sa[4] = {s4.x, s4.y, s4.z, s4.w};
    float da[4] = {d4.x, d4.y, d4.z, d4.w};
    float av[4] = {a.x, a.y, a.z, a.w};
    ushort exq[4];
    #pragma unroll
    for (int h = 0; h < 4; ++h) {
        float al = sa[h] + da[h] + av[h];
        al = al > 0.f ? al : 0.2f * al;
        exq[h] = f2bf(__expf(al));
    }
    *(uint2*)(exb + (size_t)e * 4) =
        make_uint2((uint)exq[0] | ((uint)exq[1] << 16), (uint)exq[2] | ((uint)exq[3] << 16));
}

// ---------------- lean CSR aggregation + normalize + bias + ELU + residual + LN -> bf16
__global__ __launch_bounds__(256) void k_agg2(const int* __restrict__ off,
                                              const int2* __restrict__ csr2,
                                              const ushort* __restrict__ exb,
                                              const ushort* __restrict__ xs,
                                              const float* __restrict__ bias,
                                              const ushort* __restrict__ residb,
                                              const float* __restrict__ g,
                                              const float* __restrict__ bln,
                                              ushort* __restrict__ outb)
{
    int wave = threadIdx.x >> 6;
    int lane = threadIdx.x & 63;
    int n = blockIdx.x * 4 + wave;
    if (n >= NN) return;
    int i0 = off[n], i1 = off[n + 1];
    int c0 = lane * 2;
    int h = lane >> 4;
    float a0 = 0.f, a1 = 0.f, den = 0.f;
    int i = i0;
    for (; i + 4 <= i1; i += 4) {
        int2 se0 = csr2[i], se1 = csr2[i+1], se2 = csr2[i+2], se3 = csr2[i+3];
        float w0 = bf2f(exb[(size_t)se0.y * 4 + h]);
        float w1 = bf2f(exb[(size_t)se1.y * 4 + h]);
        float w2 = bf2f(exb[(size_t)se2.y * 4 + h]);
        float w3 = bf2f(exb[(size_t)se3.y * 4 + h]);
        uint p0 = *(const uint*)(xs + (size_t)se0.x * 128 + c0);
        uint p1 = *(const uint*)(xs + (size_t)se1.x * 128 + c0);
        uint p2 = *(const uint*)(xs + (size_t)se2.x * 128 + c0);
        uint p3 = *(const uint*)(xs + (size_t)se3.x * 128 + c0);
        a0 = fmaf(bf2f(p0 & 0xffffu), w0, a0); a1 = fmaf(bf2f(p0 >> 16), w0, a1);
        a0 = fmaf(bf2f(p1 & 0xffffu), w1, a0); a1 = fmaf(bf2f(p1 >> 16), w1, a1);
        a0 = fmaf(bf2f(p2 & 0xffffu), w2, a0); a1 = fmaf(bf2f(p2 >> 16), w2, a1);
        a0 = fmaf(bf2f(p3 & 0xffffu), w3, a0); a1 = fmaf(bf2f(p3 >> 16), w3, a1);
        den += (w0 + w1) + (w2 + w3);
    }
    for (; i < i1; ++i) {
        int2 se0 = csr2[i];
        float w0 = bf2f(exb[(size_t)se0.y * 4 + h]);
        uint p0 = *(const uint*)(xs + (size_t)se0.x * 128 + c0);
        a0 = fmaf(bf2f(p0 & 0xffffu), w0, a0);
        a1 = fmaf(bf2f(p0 >> 16), w0, a1);
        den += w0;
    }
    float inv = 1.f / (den + 1e-16f);
    float v0 = a0 * inv + bias[c0];
    float v1 = a1 * inv + bias[c0 + 1];
    v0 = v0 > 0.f ? v0 : (__expf(v0) - 1.f);
    v1 = v1 > 0.f ? v1 : (__expf(v1) - 1.f);
    uint rp = *(const uint*)(residb + (size_t)n * 384 + c0);
    float r0 = v0 + bf2f(rp & 0xffffu);
    float r1 = v1 + bf2f(rp >> 16);
    float ssum = r0 + r1, ssq = r0 * r0 + r1 * r1;
    #pragma unroll
    for (int o = 1; o < 64; o <<= 1) {
        ssum += __shfl_xor(ssum, o, 64);
        ssq  += __shfl_xor(ssq, o, 64);
    }
    float mu = ssum * (1.f / 128.f);
    float var = ssq * (1.f / 128.f) - mu * mu;
    float rs = rsqrtf(var + 1e-5f);
    float o0 = (r0 - mu) * rs * g[c0] + bln[c0];
    float o1 = (r1 - mu) * rs * g[c0 + 1] + bln[c0 + 1];
    uint pk = (uint)f2bf(o0) | ((uint)f2bf(o1) << 16);
    *(uint*)(outb + (size_t)n * 384 + c0) = pk;
}

// ---------------- fused jk+classifier: out = log_softmax(hcat @ CW^T + cbp)
__global__ __launch_bounds__(256) void k_cls(const ushort* __restrict__ hcatb,
                                             const float* __restrict__ CW,
                                             const float* __restrict__ cbp,
                                             float* __restrict__ out)
{
    __shared__ float sCW[1920], scb[5];
    int t = threadIdx.x;
    for (int i = t; i < 1920; i += 256) sCW[i] = CW[i];
    if (t < 5) scb[t] = cbp[t];
    __syncthreads();
    int n = blockIdx.x * 256 + t;
    if (n >= NN) return;
    float acc[5] = {scb[0], scb[1], scb[2], scb[3], scb[4]};
    const uint2* hr = (const uint2*)(hcatb + (size_t)n * 384);
    #pragma unroll 4
    for (int q = 0; q < 96; ++q) {
        uint2 p = hr[q];
        float v0 = bf2f(p.x & 0xffffu), v1 = bf2f(p.x >> 16);
        float v2 = bf2f(p.y & 0xffffu), v3 = bf2f(p.y >> 16);
        #pragma unroll
        for (int o = 0; o < 5; ++o) {
            const float* w = sCW + o * 384 + q * 4;
            acc[o] += v0*w[0] + v1*w[1] + v2*w[2] + v3*w[3];
        }
    }
    float m = acc[0];
    #pragma unroll
    for (int o = 1; o < 5; ++o) m = fmaxf(m, acc[o]);
    float sum = 0.f;
    #pragma unroll
    for (int o = 0; o < 5; ++o) sum += __expf(acc[o] - m);
    float lse = __logf(sum) + m;
    float* op = out + (size_t)n * 5;
    #pragma unroll
    for (int o = 0; o < 5; ++o) op[o] = acc[o] - lse;
}

extern "C" void kernel_launch(void* const* d_in, const int* in_sizes, int n_in,
                              void* d_out, int out_size, void* d_ws, size_t ws_size,
                              hipStream_t stream)
{
    (void)in_sizes; (void)n_in; (void)out_size; (void)ws_size;
    const float* x        = (const float*)d_in[0];
    const int*   ei       = (const int*)d_in[1];
    const float* eattr    = (const float*)d_in[2];
    const float* ee_w1    = (const float*)d_in[3];
    const float* ee_b1    = (const float*)d_in[4];
    const float* ee_w2    = (const float*)d_in[5];
    const float* ee_b2    = (const float*)d_in[6];
    const float* proj_w   = (const float*)d_in[7];
    const float* proj_b   = (const float*)d_in[8];
    const float* c1_lin   = (const float*)d_in[9];
    const float* c1_asrc  = (const float*)d_in[10];
    const float* c1_adst  = (const float*)d_in[11];
    const float* c1_ledge = (const float*)d_in[12];
    const float* c1_aedge = (const float*)d_in[13];
    const float* c1_bias  = (const float*)d_in[14];
    const float* c2_lin   = (const float*)d_in[15];
    const float* c2_asrc  = (const float*)d_in[16];
    const float* c2_adst  = (const float*)d_in[17];
    const float* c2_ledge = (const float*)d_in[18];
    const float* c2_aedge = (const float*)d_in[19];
    const float* c2_bias  = (const float*)d_in[20];
    const float* n1_g     = (const float*)d_in[21];
    const float* n1_b     = (const float*)d_in[22];
    const float* n2_g     = (const float*)d_in[23];
    const float* n2_b     = (const float*)d_in[24];
    const float* jk_w     = (const float*)d_in[25];
    const float* jk_b     = (const float*)d_in[26];
    const float* cls_w    = (const float*)d_in[27];
    const float* cls_b    = (const float*)d_in[28];
    float* out = (float*)d_out;
    float* ws  = (float*)d_ws;

    // ---- workspace layout (float-element offsets, 16B-aligned)
    const size_t oM   = 0;                           // 32 (+pad)
    const size_t oCW  = 64;                          // 1920
    const size_t oCB  = 1984;                        // 5 (+pad to 2048)
    const size_t oV   = 2048;                        // 128 (Vs1|Vd1)
    const size_t oEX  = 2176;                        // exb bf16 NE*4 us = NE*2 f
    const size_t oAE2 = oEX + (size_t)NE * 2;        // ae2 float4: NE*4 f
    const size_t oHB  = oAE2 + (size_t)NE * 4;       // hcatb bf16 NN*384 us = NN*192 f
    const size_t oXS  = oHB + (size_t)NN * 192;      // xs bf16 NN*128 us = NN*64 f
    const size_t oWB  = oXS + (size_t)NN * 64;       // w01b 8192us + c2b 16384us = 12288 f
    const size_t oAS  = oWB + 12288;                 // NN*4
    const size_t oAD  = oAS + (size_t)NN * 4;        // NN*4
    const size_t oI   = oAD + (size_t)NN * 4;        // int region

    float*  Mmat  = ws + oM;
    float*  CW    = ws + oCW;
    float*  cbp   = ws + oCB;
    float*  Vmat  = ws + oV;
    ushort* exb   = (ushort*)(ws + oEX);
    float4* ae2   = (float4*)(ws + oAE2);
    ushort* hcatb = (ushort*)(ws + oHB);
    ushort* xs    = (ushort*)(ws + oXS);
    ushort* w01b  = (ushort*)(ws + oWB);             // [256,32]
    ushort* c2b   = w01b + 8192;                     // [128,128]
    float*  as_b  = ws + oAS;
    float*  ad_b  = ws + oAD;
    int*    ip    = (int*)(ws + oI);
    int*    deg   = ip;                              // NN
    int*    loc   = ip + NN;                         // NN
    int*    off   = ip + 2 * NN;                     // NN+16
    int*    cur   = ip + 3 * NN + 16;                // NN
    int*    bsum  = ip + 4 * NN + 16;                // 256
    int*    bcar  = ip + 4 * NN + 272;               // 256
    int2*   csr2  = (int2*)(ip + 4 * NN + 528);      // NE int2

    const int EB  = (NE + 255) / 256;          // 3125
    const int NB  = (NN + 255) / 256;          // 196
    const int GB  = (NN + 127) / 128;          // 391
    const int WB2 = (NN + 3) / 4;              // 12500

    // ---- precompute (M, CW, cbp, bf16 weights, Vs1/Vd1) + deg zero
    k_prep2<<<NB, 256, 0, stream>>>(c1_ledge, c1_aedge, c2_ledge, c2_aedge,
                                    jk_w, jk_b, cls_w, cls_b,
                                    proj_w, c1_lin, c2_lin, c1_asrc, c1_adst,
                                    Mmat, CW, cbp, w01b, c2b, Vmat, deg);
    // ---- conv1 attention coefficients directly from x
    k_att1<<<NB, 256, 0, stream>>>(x, Vmat, as_b, ad_b);
    // ---- edge MLP + conv1 ex + conv2 a_edge + dst histogram
    k_edge_mlp<<<EB, 256, 0, stream>>>(eattr, ee_w1, ee_b1, ee_w2, ee_b2, ei,
                                       Mmat, as_b, ad_b, deg, exb, ae2);
    // ---- CSR offsets + scatter
    k_scan_blk<<<NB, 256, 0, stream>>>(deg, loc, bsum);
    k_scan_top<<<1, 256, 0, stream>>>(bsum, bcar, off + NN, NB);
    k_scan_add<<<NB, 256, 0, stream>>>(loc, bcar, off, cur);
    k_scatter2<<<EB, 256, 0, stream>>>(ei, cur, csr2);

    // ---- h0 + xs1 in one pass from fp32 x
    k_gemm1<<<GB, 256, 0, stream>>>(x, w01b, proj_b, hcatb, xs, NN);

    // ---- conv1 aggregation (ex precomputed)
    k_agg2<<<WB2, 256, 0, stream>>>(off, csr2, exb, xs, c1_bias, hcatb,
                                    n1_g, n1_b, hcatb + 128);

    // ---- conv2
    gemm_bf16<<<GB, 256, 0, stream>>>(hcatb + 128, 384, 128, c2b, 128, xs, 128, NN);
    k_att_reduce<<<NB, 256, 0, stream>>>(xs, c2_asrc, c2_adst, as_b, ad_b);
    k_edge_soft2<<<EB, 256, 0, stream>>>(ei, as_b, ad_b, ae2, exb);
    k_agg2<<<WB2, 256, 0, stream>>>(off, csr2, exb, xs, c2_bias, hcatb + 128,
                                    n2_g, n2_b, hcatb + 256);

    // ---- fused jk+classifier+log_softmax
    k_cls<<<NB, 256, 0, stream>>>(hcatb, CW, cbp, out);
}

// Round 7
// 394.469 us; speedup vs baseline: 8.5413x; 1.0088x over previous
//
#include <hip/hip_runtime.h>
#include <cstdint>

#define NN 50000
#define NE 800000
#define DPX 6250            // dst-partition size per XCD (NN/8)
#define SLICES 391          // ceil(NE/2048)

using short8  = __attribute__((ext_vector_type(8))) short;
using float4v = __attribute__((ext_vector_type(4))) float;

__device__ __forceinline__ ushort f2bf(float f) {
    uint u = __float_as_uint(f);
    uint r = (u + 0x7fffu + ((u >> 16) & 1u)) >> 16;
    return (ushort)r;
}
__device__ __forceinline__ float bf2f(uint u) {
    return __uint_as_float(u << 16);
}

// ---------------- fused tiny precompute + weight cvt + deg zero
__global__ __launch_bounds__(256) void k_prep2(const float* __restrict__ le1, const float* __restrict__ ae1,
                                               const float* __restrict__ le2, const float* __restrict__ ae2,
                                               const float* __restrict__ jkw, const float* __restrict__ jkb,
                                               const float* __restrict__ clw, const float* __restrict__ clb,
                                               const float* __restrict__ projw, const float* __restrict__ c1lin,
                                               const float* __restrict__ c2lin,
                                               const float* __restrict__ asrc1, const float* __restrict__ adst1,
                                               float* __restrict__ M, float* __restrict__ CW,
                                               float* __restrict__ cbp,
                                               ushort* __restrict__ w01b, ushort* __restrict__ c2b,
                                               float* __restrict__ Vmat, int* __restrict__ deg)
{
    int idx = blockIdx.x * 256 + threadIdx.x;
    if (idx < NN) deg[idx] = 0;
    if (idx < 32) {
        const float* le = (idx < 16) ? le1 : le2;
        const float* ae = (idx < 16) ? ae1 : ae2;
        int hk = idx & 15, h = hk >> 2, k = hk & 3;
        float s = 0.f;
        for (int c = 0; c < 32; ++c)
            s += le[(h * 32 + c) * 4 + k] * ae[h * 32 + c];
        M[idx] = s;
    } else if (idx < 1952) {
        int o = idx - 32;
        int r = o / 384, c = o - r * 384;
        float s = 0.f;
        for (int k = 0; k < 128; ++k)
            s += clw[r * 128 + k] * jkw[(size_t)k * 384 + c];
        CW[o] = s;
    } else if (idx < 1957) {
        int r = idx - 1952;
        float s = clb[r];
        for (int k = 0; k < 128; ++k)
            s += clw[r * 128 + k] * jkb[k];
        cbp[r] = s;
    } else if (idx >= 2048 && idx < 10240) {
        int o = idx - 2048;
        int r = o >> 5, c = o & 31;
        float v = 0.f;
        if (c < 16) v = (r < 128) ? projw[r * 16 + c] : c1lin[(r - 128) * 16 + c];
        w01b[o] = f2bf(v);
    } else if (idx >= 10240 && idx < 26624) {
        int o = idx - 10240;
        c2b[o] = f2bf(c2lin[o]);
    } else if (idx >= 26624 && idx < 26752) {
        int o = idx - 26624;
        const float* att = (o < 64) ? asrc1 : adst1;
        int oo = o & 63, h = oo >> 4, k = oo & 15;
        float s = 0.f;
        for (int c = 0; c < 32; ++c)
            s += c1lin[(h * 32 + c) * 16 + k] * att[h * 32 + c];
        Vmat[o] = s;
    }
}

// ---------------- conv1 attention coefficients straight from x
__global__ __launch_bounds__(256) void k_att1(const float* __restrict__ x,
                                              const float* __restrict__ V,
                                              float* __restrict__ as_o,
                                              float* __restrict__ ad_o)
{
    __shared__ float sV[128];
    int t = threadIdx.x;
    if (t < 128) sV[t] = V[t];
    __syncthreads();
    int n = blockIdx.x * 256 + t;
    if (n >= NN) return;
    const float4* xr = (const float4*)(x + (size_t)n * 16);
    float4 x0 = xr[0], x1 = xr[1], x2 = xr[2], x3 = xr[3];
    float xv[16] = {x0.x,x0.y,x0.z,x0.w, x1.x,x1.y,x1.z,x1.w,
                    x2.x,x2.y,x2.z,x2.w, x3.x,x3.y,x3.z,x3.w};
    float s[4], d[4];
    #pragma unroll
    for (int h = 0; h < 4; ++h) {
        float ss = 0.f, dd = 0.f;
        #pragma unroll
        for (int k = 0; k < 16; ++k) {
            ss += xv[k] * sV[h * 16 + k];
            dd += xv[k] * sV[64 + h * 16 + k];
        }
        s[h] = ss; d[h] = dd;
    }
    *(float4*)(as_o + (size_t)n * 4) = make_float4(s[0], s[1], s[2], s[3]);
    *(float4*)(ad_o + (size_t)n * 4) = make_float4(d[0], d[1], d[2], d[3]);
}

// ---------------- edge MLP + conv1 ex (bf16) + conv2 a_edge (bf16); NO histogram
__global__ __launch_bounds__(256) void k_edge_mlp(const float* __restrict__ ea,
                                                  const float* __restrict__ w1,
                                                  const float* __restrict__ b1,
                                                  const float* __restrict__ w2,
                                                  const float* __restrict__ b2,
                                                  const int* __restrict__ ei,
                                                  const float* __restrict__ Mm,
                                                  const float* __restrict__ as1,
                                                  const float* __restrict__ ad1,
                                                  ushort* __restrict__ exb,
                                                  ushort* __restrict__ ae2)
{
    __shared__ float sw1[256], sb1[32], sw2[128], sb2[4], sM[32];
    int t = threadIdx.x;
    sw1[t] = w1[t];
    if (t < 128) sw2[t] = w2[t];
    if (t < 32)  { sb1[t] = b1[t]; sM[t] = Mm[t]; }
    if (t < 4)   sb2[t] = b2[t];
    __syncthreads();
    int e = blockIdx.x * 256 + t;
    if (e >= NE) return;
    int src = ei[e], dst = ei[NE + e];
    float4 s4 = *(const float4*)(as1 + (size_t)src * 4);
    float4 d4 = *(const float4*)(ad1 + (size_t)dst * 4);
    float4 x0 = *(const float4*)(ea + (size_t)e * 8);
    float4 x1 = *(const float4*)(ea + (size_t)e * 8 + 4);
    float o0 = sb2[0], o1 = sb2[1], o2 = sb2[2], o3 = sb2[3];
    #pragma unroll
    for (int j = 0; j < 32; ++j) {
        const float* w = sw1 + j * 8;
        float s = sb1[j] + w[0]*x0.x + w[1]*x0.y + w[2]*x0.z + w[3]*x0.w
                         + w[4]*x1.x + w[5]*x1.y + w[6]*x1.z + w[7]*x1.w;
        s = fmaxf(s, 0.f);
        o0 += sw2[0*32+j] * s; o1 += sw2[1*32+j] * s;
        o2 += sw2[2*32+j] * s; o3 += sw2[3*32+j] * s;
    }
    float sa[4] = {s4.x, s4.y, s4.z, s4.w};
    float da[4] = {d4.x, d4.y, d4.z, d4.w};
    ushort exq[4], a2q[4];
    #pragma unroll
    for (int h = 0; h < 4; ++h) {
        float ae1 = sM[h*4+0]*o0 + sM[h*4+1]*o1 + sM[h*4+2]*o2 + sM[h*4+3]*o3;
        float al = sa[h] + da[h] + ae1;
        al = al > 0.f ? al : 0.2f * al;
        exq[h] = f2bf(__expf(al));
        a2q[h] = f2bf(sM[16+h*4+0]*o0 + sM[16+h*4+1]*o1 + sM[16+h*4+2]*o2 + sM[16+h*4+3]*o3);
    }
    *(uint2*)(exb + (size_t)e * 4) =
        make_uint2((uint)exq[0] | ((uint)exq[1] << 16), (uint)exq[2] | ((uint)exq[3] << 16));
    *(uint2*)(ae2 + (size_t)e * 4) =
        make_uint2((uint)a2q[0] | ((uint)a2q[1] << 16), (uint)a2q[2] | ((uint)a2q[3] << 16));
}

// ---------------- XCD-partitioned histogram: group = blockIdx&7 owns dst range
__global__ __launch_bounds__(256) void k_hist8(const int* __restrict__ ei, int* __restrict__ deg)
{
    int grp = blockIdx.x & 7;
    int base = (blockIdx.x >> 3) * 2048 + threadIdx.x;
    #pragma unroll
    for (int k = 0; k < 8; ++k) {
        int e = base + k * 256;
        if (e < NE) {
            int dst = ei[NE + e];
            if (dst / DPX == grp) atomicAdd(&deg[dst], 1);
        }
    }
}

// ---------------- scan ----------------
__global__ __launch_bounds__(256) void k_scan_blk(const int* __restrict__ deg,
                                                  int* __restrict__ loc,
                                                  int* __restrict__ bsum)
{
    __shared__ int tmp[256];
    int t = threadIdx.x;
    int i = blockIdx.x * 256 + t;
    int v = (i < NN) ? deg[i] : 0;
    tmp[t] = v;
    __syncthreads();
    #pragma unroll
    for (int o = 1; o < 256; o <<= 1) {
        int add = (t >= o) ? tmp[t - o] : 0;
        __syncthreads();
        tmp[t] += add;
        __syncthreads();
    }
    if (i < NN) loc[i] = tmp[t] - v;
    if (t == 255) bsum[blockIdx.x] = tmp[255];
}

__global__ __launch_bounds__(256) void k_scan_top(const int* __restrict__ bsum,
                                                  int* __restrict__ bcarry,
                                                  int* __restrict__ total_out, int nb)
{
    __shared__ int tmp[256];
    int t = threadIdx.x;
    int v = (t < nb) ? bsum[t] : 0;
    tmp[t] = v;
    __syncthreads();
    #pragma unroll
    for (int o = 1; o < 256; o <<= 1) {
        int add = (t >= o) ? tmp[t - o] : 0;
        __syncthreads();
        tmp[t] += add;
        __syncthreads();
    }
    if (t < nb) bcarry[t] = tmp[t] - v;
    if (t == 255) *total_out = tmp[255];
}

__global__ __launch_bounds__(256) void k_scan_add(const int* __restrict__ loc,
                                                  const int* __restrict__ bcarry,
                                                  int* __restrict__ off,
                                                  int* __restrict__ cur)
{
    int i = blockIdx.x * 256 + threadIdx.x;
    if (i < NN) {
        int o = loc[i] + bcarry[blockIdx.x];
        off[i] = o;
        cur[i] = o;
    }
}

// ---------------- XCD-partitioned scatter: group writes only its dst range -> L2-local
__global__ __launch_bounds__(256) void k_scatter8(const int* __restrict__ ei,
                                                  int* __restrict__ cursor,
                                                  int2* __restrict__ csr2)
{
    int grp = blockIdx.x & 7;
    int base = (blockIdx.x >> 3) * 2048 + threadIdx.x;
    #pragma unroll
    for (int k = 0; k < 8; ++k) {
        int e = base + k * 256;
        if (e < NE) {
            int dst = ei[NE + e];
            if (dst / DPX == grp) {
                int src = ei[e];
                int p = atomicAdd(&cursor[dst], 1);
                csr2[p] = make_int2(src, e);
            }
        }
    }
}

// ---------------- fused GEMM pair from x (K=16 pad 32): h0 -> hcatb[:,0:128]; xs1 -> xs
__global__ __launch_bounds__(256) void k_gemm1(const float* __restrict__ x,
                                               const ushort* __restrict__ w01,
                                               const float* __restrict__ pbias,
                                               ushort* __restrict__ hcatb,
                                               ushort* __restrict__ xs, int M)
{
    int t = threadIdx.x;
    int wv = t >> 6, lane = t & 63;
    int quad = lane >> 4, r16 = lane & 15;
    int m0 = blockIdx.x * 128 + wv * 32;
    int ar0 = m0 + r16;      if (ar0 >= M) ar0 = M - 1;
    int ar1 = m0 + 16 + r16; if (ar1 >= M) ar1 = M - 1;
    short8 a0 = (short8){0,0,0,0,0,0,0,0}, a1 = a0;
    if (quad < 2) {
        const float* p0 = x + (size_t)ar0 * 16 + quad * 8;
        const float* p1 = x + (size_t)ar1 * 16 + quad * 8;
        float4 u0 = *(const float4*)p0, u1 = *(const float4*)(p0 + 4);
        float4 v0 = *(const float4*)p1, v1 = *(const float4*)(p1 + 4);
        a0[0]=(short)f2bf(u0.x); a0[1]=(short)f2bf(u0.y); a0[2]=(short)f2bf(u0.z); a0[3]=(short)f2bf(u0.w);
        a0[4]=(short)f2bf(u1.x); a0[5]=(short)f2bf(u1.y); a0[6]=(short)f2bf(u1.z); a0[7]=(short)f2bf(u1.w);
        a1[0]=(short)f2bf(v0.x); a1[1]=(short)f2bf(v0.y); a1[2]=(short)f2bf(v0.z); a1[3]=(short)f2bf(v0.w);
        a1[4]=(short)f2bf(v1.x); a1[5]=(short)f2bf(v1.y); a1[6]=(short)f2bf(v1.z); a1[7]=(short)f2bf(v1.w);
    }
    float4v acc[2][16];
    #pragma unroll
    for (int i = 0; i < 2; ++i)
        #pragma unroll
        for (int j = 0; j < 16; ++j) acc[i][j] = (float4v){0.f, 0.f, 0.f, 0.f};
    #pragma unroll
    for (int nt = 0; nt < 16; ++nt) {
        short8 b = *(const short8*)(w01 + (size_t)(nt * 16 + r16) * 32 + quad * 8);
        acc[0][nt] = __builtin_amdgcn_mfma_f32_16x16x32_bf16(a0, b, acc[0][nt], 0, 0, 0);
        acc[1][nt] = __builtin_amdgcn_mfma_f32_16x16x32_bf16(a1, b, acc[1][nt], 0, 0, 0);
    }
    #pragma unroll
    for (int rt = 0; rt < 2; ++rt) {
        #pragma unroll
        for (int nt = 0; nt < 16; ++nt) {
            int col = (nt & 7) * 16 + r16;
            float bv = (nt < 8) ? pbias[col] : 0.f;
            #pragma unroll
            for (int r = 0; r < 4; ++r) {
                int row = m0 + rt * 16 + quad * 4 + r;
                if (row < M) {
                    float v = acc[rt][nt][r] + bv;
                    if (nt < 8) hcatb[(size_t)row * 384 + col] = f2bf(v);
                    else        xs[(size_t)row * 128 + col] = f2bf(v);
                }
            }
        }
    }
}

// ---------------- conv2 GEMM (K=128) with fused per-head att reduction epilogue
__global__ __launch_bounds__(256) void k_gemm2(const ushort* __restrict__ A,   // h1, lda=384
                                               const ushort* __restrict__ W,   // c2b, ldw=128
                                               const float* __restrict__ atts,
                                               const float* __restrict__ attd,
                                               ushort* __restrict__ xs,
                                               float* __restrict__ as_o,
                                               float* __restrict__ ad_o, int M)
{
    __shared__ float sAs[128], sAd[128];
    int t = threadIdx.x;
    if (t < 128) { sAs[t] = atts[t]; sAd[t] = attd[t]; }
    __syncthreads();
    int wv = t >> 6, lane = t & 63;
    int quad = lane >> 4, r16 = lane & 15;
    int m0 = blockIdx.x * 128 + wv * 32;
    float4v acc[2][8];
    #pragma unroll
    for (int i = 0; i < 2; ++i)
        #pragma unroll
        for (int j = 0; j < 8; ++j) acc[i][j] = (float4v){0.f, 0.f, 0.f, 0.f};
    int ar0 = m0 + r16;      if (ar0 >= M) ar0 = M - 1;
    int ar1 = m0 + 16 + r16; if (ar1 >= M) ar1 = M - 1;
    const ushort* a0p = A + (size_t)ar0 * 384 + quad * 8;
    const ushort* a1p = A + (size_t)ar1 * 384 + quad * 8;
    const ushort* wp  = W + (size_t)r16 * 128 + quad * 8;
    #pragma unroll
    for (int k0 = 0; k0 < 128; k0 += 32) {
        short8 a0 = *(const short8*)(a0p + k0);
        short8 a1 = *(const short8*)(a1p + k0);
        #pragma unroll
        for (int nt = 0; nt < 8; ++nt) {
            short8 b = *(const short8*)(wp + (size_t)(nt * 16) * 128 + k0);
            acc[0][nt] = __builtin_amdgcn_mfma_f32_16x16x32_bf16(a0, b, acc[0][nt], 0, 0, 0);
            acc[1][nt] = __builtin_amdgcn_mfma_f32_16x16x32_bf16(a1, b, acc[1][nt], 0, 0, 0);
        }
    }
    #pragma unroll
    for (int rt = 0; rt < 2; ++rt) {
        #pragma unroll
        for (int nt = 0; nt < 8; ++nt) {
            int col = nt * 16 + r16;
            #pragma unroll
            for (int r = 0; r < 4; ++r) {
                int row = m0 + rt * 16 + quad * 4 + r;
                if (row < M)
                    xs[(size_t)row * 128 + col] = f2bf(acc[rt][nt][r]);
            }
        }
        // fused att_src/att_dst per-head reduction (16-lane groups share a row)
        #pragma unroll
        for (int r = 0; r < 4; ++r) {
            int row = m0 + rt * 16 + quad * 4 + r;
            float sh[4], dh[4];
            #pragma unroll
            for (int h = 0; h < 4; ++h) {
                int cA = h * 32 + r16, cB = cA + 16;
                sh[h] = acc[rt][2*h][r] * sAs[cA] + acc[rt][2*h+1][r] * sAs[cB];
                dh[h] = acc[rt][2*h][r] * sAd[cA] + acc[rt][2*h+1][r] * sAd[cB];
            }
            #pragma unroll
            for (int o = 1; o < 16; o <<= 1) {
                #pragma unroll
                for (int h = 0; h < 4; ++h) {
                    sh[h] += __shfl_xor(sh[h], o, 64);
                    dh[h] += __shfl_xor(dh[h], o, 64);
                }
            }
            if (r16 == 0 && row < M) {
                *(float4*)(as_o + (size_t)row * 4) = make_float4(sh[0], sh[1], sh[2], sh[3]);
                *(float4*)(ad_o + (size_t)row * 4) = make_float4(dh[0], dh[1], dh[2], dh[3]);
            }
        }
    }
}

// ---------------- conv2 softmax numerator: ex = exp(leaky(ae2 + as[src] + ad[dst])) -> bf16
__global__ __launch_bounds__(256) void k_edge_soft2(const int* __restrict__ ei,
                                                    const float* __restrict__ as_in,
                                                    const float* __restrict__ ad_in,
                                                    const ushort* __restrict__ ae2,
                                                    ushort* __restrict__ exb)
{
    int e = blockIdx.x * 256 + threadIdx.x;
    if (e >= NE) return;
    int src = ei[e], dst = ei[NE + e];
    float4 s4 = *(const float4*)(as_in + (size_t)src * 4);
    float4 d4 = *(const float4*)(ad_in + (size_t)dst * 4);
    uint2 aq = *(const uint2*)(ae2 + (size_t)e * 4);
    float av[4] = {bf2f(aq.x & 0xffffu), bf2f(aq.x >> 16), bf2f(aq.y & 0xffffu), bf2f(aq.y >> 16)};
    float sa[4] = {s4.x, s4.y, s4.z, s4.w};
    float da[4] = {d4.x, d4.y, d4.z, d4.w};
    ushort exq[4];
    #pragma unroll
    for (int h = 0; h < 4; ++h) {
        float al = sa[h] + da[h] + av[h];
        al = al > 0.f ? al : 0.2f * al;
        exq[h] = f2bf(__expf(al));
    }
    *(uint2*)(exb + (size_t)e * 4) =
        make_uint2((uint)exq[0] | ((uint)exq[1] << 16), (uint)exq[2] | ((uint)exq[3] << 16));
}

// ---------------- lean CSR aggregation + normalize + bias + ELU + residual + LN -> bf16
__global__ __launch_bounds__(256) void k_agg2(const int* __restrict__ off,
                                              const int2* __restrict__ csr2,
                                              const ushort* __restrict__ exb,
                                              const ushort* __restrict__ xs,
                                              const float* __restrict__ bias,
                                              const ushort* __restrict__ residb,
                                              const float* __restrict__ g,
                                              const float* __restrict__ bln,
                                              ushort* __restrict__ outb)
{
    int wave = threadIdx.x >> 6;
    int lane = threadIdx.x & 63;
    int n = blockIdx.x * 4 + wave;
    if (n >= NN) return;
    int i0 = off[n], i1 = off[n + 1];
    int c0 = lane * 2;
    int h = lane >> 4;
    float a0 = 0.f, a1 = 0.f, den = 0.f;
    int i = i0;
    for (; i + 4 <= i1; i += 4) {
        int2 se0 = csr2[i], se1 = csr2[i+1], se2 = csr2[i+2], se3 = csr2[i+3];
        float w0 = bf2f(exb[(size_t)se0.y * 4 + h]);
        float w1 = bf2f(exb[(size_t)se1.y * 4 + h]);
        float w2 = bf2f(exb[(size_t)se2.y * 4 + h]);
        float w3 = bf2f(exb[(size_t)se3.y * 4 + h]);
        uint p0 = *(const uint*)(xs + (size_t)se0.x * 128 + c0);
        uint p1 = *(const uint*)(xs + (size_t)se1.x * 128 + c0);
        uint p2 = *(const uint*)(xs + (size_t)se2.x * 128 + c0);
        uint p3 = *(const uint*)(xs + (size_t)se3.x * 128 + c0);
        a0 = fmaf(bf2f(p0 & 0xffffu), w0, a0); a1 = fmaf(bf2f(p0 >> 16), w0, a1);
        a0 = fmaf(bf2f(p1 & 0xffffu), w1, a0); a1 = fmaf(bf2f(p1 >> 16), w1, a1);
        a0 = fmaf(bf2f(p2 & 0xffffu), w2, a0); a1 = fmaf(bf2f(p2 >> 16), w2, a1);
        a0 = fmaf(bf2f(p3 & 0xffffu), w3, a0); a1 = fmaf(bf2f(p3 >> 16), w3, a1);
        den += (w0 + w1) + (w2 + w3);
    }
    for (; i < i1; ++i) {
        int2 se0 = csr2[i];
        float w0 = bf2f(exb[(size_t)se0.y * 4 + h]);
        uint p0 = *(const uint*)(xs + (size_t)se0.x * 128 + c0);
        a0 = fmaf(bf2f(p0 & 0xffffu), w0, a0);
        a1 = fmaf(bf2f(p0 >> 16), w0, a1);
        den += w0;
    }
    float inv = 1.f / (den + 1e-16f);
    float v0 = a0 * inv + bias[c0];
    float v1 = a1 * inv + bias[c0 + 1];
    v0 = v0 > 0.f ? v0 : (__expf(v0) - 1.f);
    v1 = v1 > 0.f ? v1 : (__expf(v1) - 1.f);
    uint rp = *(const uint*)(residb + (size_t)n * 384 + c0);
    float r0 = v0 + bf2f(rp & 0xffffu);
    float r1 = v1 + bf2f(rp >> 16);
    float ssum = r0 + r1, ssq = r0 * r0 + r1 * r1;
    #pragma unroll
    for (int o = 1; o < 64; o <<= 1) {
        ssum += __shfl_xor(ssum, o, 64);
        ssq  += __shfl_xor(ssq, o, 64);
    }
    float mu = ssum * (1.f / 128.f);
    float var = ssq * (1.f / 128.f) - mu * mu;
    float rs = rsqrtf(var + 1e-5f);
    float o0 = (r0 - mu) * rs * g[c0] + bln[c0];
    float o1 = (r1 - mu) * rs * g[c0 + 1] + bln[c0 + 1];
    uint pk = (uint)f2bf(o0) | ((uint)f2bf(o1) << 16);
    *(uint*)(outb + (size_t)n * 384 + c0) = pk;
}

// ---------------- fused jk+classifier: out = log_softmax(hcat @ CW^T + cbp)
__global__ __launch_bounds__(256) void k_cls(const ushort* __restrict__ hcatb,
                                             const float* __restrict__ CW,
                                             const float* __restrict__ cbp,
                                             float* __restrict__ out)
{
    __shared__ float sCW[1920], scb[5];
    int t = threadIdx.x;
    for (int i = t; i < 1920; i += 256) sCW[i] = CW[i];
    if (t < 5) scb[t] = cbp[t];
    __syncthreads();
    int n = blockIdx.x * 256 + t;
    if (n >= NN) return;
    float acc[5] = {scb[0], scb[1], scb[2], scb[3], scb[4]};
    const uint2* hr = (const uint2*)(hcatb + (size_t)n * 384);
    #pragma unroll 4
    for (int q = 0; q < 96; ++q) {
        uint2 p = hr[q];
        float v0 = bf2f(p.x & 0xffffu), v1 = bf2f(p.x >> 16);
        float v2 = bf2f(p.y & 0xffffu), v3 = bf2f(p.y >> 16);
        #pragma unroll
        for (int o = 0; o < 5; ++o) {
            const float* w = sCW + o * 384 + q * 4;
            acc[o] += v0*w[0] + v1*w[1] + v2*w[2] + v3*w[3];
        }
    }
    float m = acc[0];
    #pragma unroll
    for (int o = 1; o < 5; ++o) m = fmaxf(m, acc[o]);
    float sum = 0.f;
    #pragma unroll
    for (int o = 0; o < 5; ++o) sum += __expf(acc[o] - m);
    float lse = __logf(sum) + m;
    float* op = out + (size_t)n * 5;
    #pragma unroll
    for (int o = 0; o < 5; ++o) op[o] = acc[o] - lse;
}

extern "C" void kernel_launch(void* const* d_in, const int* in_sizes, int n_in,
                              void* d_out, int out_size, void* d_ws, size_t ws_size,
                              hipStream_t stream)
{
    (void)in_sizes; (void)n_in; (void)out_size; (void)ws_size;
    const float* x        = (const float*)d_in[0];
    const int*   ei       = (const int*)d_in[1];
    const float* eattr    = (const float*)d_in[2];
    const float* ee_w1    = (const float*)d_in[3];
    const float* ee_b1    = (const float*)d_in[4];
    const float* ee_w2    = (const float*)d_in[5];
    const float* ee_b2    = (const float*)d_in[6];
    const float* proj_w   = (const float*)d_in[7];
    const float* proj_b   = (const float*)d_in[8];
    const float* c1_lin   = (const float*)d_in[9];
    const float* c1_asrc  = (const float*)d_in[10];
    const float* c1_adst  = (const float*)d_in[11];
    const float* c1_ledge = (const float*)d_in[12];
    const float* c1_aedge = (const float*)d_in[13];
    const float* c1_bias  = (const float*)d_in[14];
    const float* c2_lin   = (const float*)d_in[15];
    const float* c2_asrc  = (const float*)d_in[16];
    const float* c2_adst  = (const float*)d_in[17];
    const float* c2_ledge = (const float*)d_in[18];
    const float* c2_aedge = (const float*)d_in[19];
    const float* c2_bias  = (const float*)d_in[20];
    const float* n1_g     = (const float*)d_in[21];
    const float* n1_b     = (const float*)d_in[22];
    const float* n2_g     = (const float*)d_in[23];
    const float* n2_b     = (const float*)d_in[24];
    const float* jk_w     = (const float*)d_in[25];
    const float* jk_b     = (const float*)d_in[26];
    const float* cls_w    = (const float*)d_in[27];
    const float* cls_b    = (const float*)d_in[28];
    float* out = (float*)d_out;
    float* ws  = (float*)d_ws;

    // ---- workspace layout (float-element offsets, 16B-aligned)
    const size_t oM   = 0;                           // 32 (+pad)
    const size_t oCW  = 64;                          // 1920
    const size_t oCB  = 1984;                        // 5 (+pad to 2048)
    const size_t oV   = 2048;                        // 128 (Vs1|Vd1)
    const size_t oEX  = 2176;                        // exb bf16 NE*4 us = NE*2 f
    const size_t oAE2 = oEX + (size_t)NE * 2;        // ae2 bf16 NE*4 us = NE*2 f
    const size_t oHB  = oAE2 + (size_t)NE * 2;       // hcatb bf16 NN*384 us = NN*192 f
    const size_t oXS  = oHB + (size_t)NN * 192;      // xs bf16 NN*128 us = NN*64 f
    const size_t oWB  = oXS + (size_t)NN * 64;       // w01b 8192us + c2b 16384us = 12288 f
    const size_t oAS  = oWB + 12288;                 // NN*4
    const size_t oAD  = oAS + (size_t)NN * 4;        // NN*4
    const size_t oI   = oAD + (size_t)NN * 4;        // int region

    float*  Mmat  = ws + oM;
    float*  CW    = ws + oCW;
    float*  cbp   = ws + oCB;
    float*  Vmat  = ws + oV;
    ushort* exb   = (ushort*)(ws + oEX);
    ushort* ae2b  = (ushort*)(ws + oAE2);
    ushort* hcatb = (ushort*)(ws + oHB);
    ushort* xs    = (ushort*)(ws + oXS);
    ushort* w01b  = (ushort*)(ws + oWB);             // [256,32]
    ushort* c2b   = w01b + 8192;                     // [128,128]
    float*  as_b  = ws + oAS;
    float*  ad_b  = ws + oAD;
    int*    ip    = (int*)(ws + oI);
    int*    deg   = ip;                              // NN
    int*    loc   = ip + NN;                         // NN
    int*    off   = ip + 2 * NN;                     // NN+16
    int*    cur   = ip + 3 * NN + 16;                // NN
    int*    bsum  = ip + 4 * NN + 16;                // 256
    int*    bcar  = ip + 4 * NN + 272;               // 256
    int2*   csr2  = (int2*)(ip + 4 * NN + 528);      // NE int2

    const int EB  = (NE + 255) / 256;          // 3125
    const int NB  = (NN + 255) / 256;          // 196
    const int GB  = (NN + 127) / 128;          // 391
    const int WB2 = (NN + 3) / 4;              // 12500
    const int PB  = SLICES * 8;                // 3128 partitioned blocks

    // ---- precompute (M, CW, cbp, bf16 weights, Vs1/Vd1) + deg zero
    k_prep2<<<NB, 256, 0, stream>>>(c1_ledge, c1_aedge, c2_ledge, c2_aedge,
                                    jk_w, jk_b, cls_w, cls_b,
                                    proj_w, c1_lin, c2_lin, c1_asrc, c1_adst,
                                    Mmat, CW, cbp, w01b, c2b, Vmat, deg);
    // ---- XCD-partitioned CSR build
    k_hist8<<<PB, 256, 0, stream>>>(ei, deg);
    k_scan_blk<<<NB, 256, 0, stream>>>(deg, loc, bsum);
    k_scan_top<<<1, 256, 0, stream>>>(bsum, bcar, off + NN, NB);
    k_scan_add<<<NB, 256, 0, stream>>>(loc, bcar, off, cur);
    k_scatter8<<<PB, 256, 0, stream>>>(ei, cur, csr2);

    // ---- conv1 attention coefficients from x; edge MLP (ex1 + ae2)
    k_att1<<<NB, 256, 0, stream>>>(x, Vmat, as_b, ad_b);
    k_edge_mlp<<<EB, 256, 0, stream>>>(eattr, ee_w1, ee_b1, ee_w2, ee_b2, ei,
                                       Mmat, as_b, ad_b, exb, ae2b);

    // ---- h0 + xs1 in one pass from fp32 x
    k_gemm1<<<GB, 256, 0, stream>>>(x, w01b, proj_b, hcatb, xs, NN);

    // ---- conv1 aggregation
    k_agg2<<<WB2, 256, 0, stream>>>(off, csr2, exb, xs, c1_bias, hcatb,
                                    n1_g, n1_b, hcatb + 128);

    // ---- conv2: GEMM with fused att reduction, then numerator, then aggregation
    k_gemm2<<<GB, 256, 0, stream>>>(hcatb + 128, c2b, c2_asrc, c2_adst,
                                    xs, as_b, ad_b, NN);
    k_edge_soft2<<<EB, 256, 0, stream>>>(ei, as_b, ad_b, ae2b, exb);
    k_agg2<<<WB2, 256, 0, stream>>>(off, csr2, exb, xs, c2_bias, hcatb + 128,
                                    n2_g, n2_b, hcatb + 256);

    // ---- fused jk+classifier+log_softmax
    k_cls<<<NB, 256, 0, stream>>>(hcatb, CW, cbp, out);
}